// Round 1
// 1560.032 us; speedup vs baseline: 1.0912x; 1.0912x over previous
//
#include <hip/hip_runtime.h>
#include <math.h>

// ---------------------------------------------------------------------------
// overAll_37606733644133 : relational GNN (2-layer Householder-reflection
// message passing with edge softmax) + proxy attention + gated mixing.
//
// This revision moves k_pg's three dense GEMMs (logits, pf-correction, gate)
// onto the MFMA pipe using split-bf16 (hi/lo, 3-term) arithmetic:
//   x*w ~= xh*wh + xl*wh + xh*wl   (error ~2^-16 relative, near-fp32)
// B-operands (W, l2n(proxy), proxy^T) are pre-split into bf16 hi/lo arrays
// in n-major / k-contiguous layout (16B loads per fragment). A-operands are
// packed (hi<<16|lo) u32 in LDS, converted in place (no LDS growth: 28.6 KB
// -> 5 blocks/CU preserved). MFMA layout per verified m89/m97 mapping:
//   A: row=lane&15, k=8*(lane>>4)+i (contig);  B: col=lane&15, same k
//   D: col=lane&15, row=(lane>>4)*4+reg
// ---------------------------------------------------------------------------

#define NN    50000
#define NE    800000
#define NR    2000
#define FF    128
#define FDIM  384
#define OD    768     // output row stride (2 duals x 384)
#define PP    64
#define NEPS  1e-12f
#define FSTR  388     // LDS row stride (u32) for o/pf tile: 388%32=4 -> 2-way (free)
#define ASTR  68      // LDS row stride (u32) for att tile:  68%32=4 -> 2-way (free)

typedef unsigned int u32;
typedef unsigned short u16;
typedef __attribute__((ext_vector_type(8))) short bf16x8;   // 8 bf16 (4 VGPRs)
typedef __attribute__((ext_vector_type(4))) float f32x4;

// ---- static device scratch ------------------------------------------------
__device__ int   g_rowptr[NN + 1];
__device__ int   g_cnt[NN];
__device__ u32   g_csr[NE];               // (src<<16) | rel
__device__ float g_relnorm[NR * FF];
__device__ float g_atab[4 * NR];          // 0=ent-l0,1=ent-l1,2=rel-l0,3=rel-l1
// split-bf16 B-operands, all n-major / k-contiguous:
__device__ __attribute__((aligned(16))) u16 g_wt_hi[2 * FDIM * FDIM];  // [d][f][k] = W_d[k][f]
__device__ __attribute__((aligned(16))) u16 g_wt_lo[2 * FDIM * FDIM];
__device__ __attribute__((aligned(16))) u16 g_pxn_hi[2 * PP * FDIM];   // [d][p][k] = l2n(proxy_d[p])[k]
__device__ __attribute__((aligned(16))) u16 g_pxn_lo[2 * PP * FDIM];
__device__ __attribute__((aligned(16))) u16 g_pxT_hi[2 * FDIM * PP];   // [d][f][p] = proxy_d[p][f]
__device__ __attribute__((aligned(16))) u16 g_pxT_lo[2 * FDIM * PP];

__device__ __forceinline__ float wsum64(float v) {
#pragma unroll
    for (int m = 32; m > 0; m >>= 1) v += __shfl_xor(v, m, 64);
    return v;
}
__device__ __forceinline__ float wmax64(float v) {
#pragma unroll
    for (int m = 32; m > 0; m >>= 1) v = fmaxf(v, __shfl_xor(v, m, 64));
    return v;
}

// fp32 -> (bf16_hi << 16) | bf16_lo, both RNE; hi+lo reconstructs to ~2^-16 rel
__device__ __forceinline__ u32 pack_bf(float f) {
    u32 x = __float_as_uint(f);
    u32 hr = (x + 0x7FFFu + ((x >> 16) & 1u)) & 0xFFFF0000u;
    float res = f - __uint_as_float(hr);
    u32 y = __float_as_uint(res);
    u32 lr = (y + 0x7FFFu + ((y >> 16) & 1u)) >> 16;
    return hr | lr;
}
__device__ __forceinline__ float unpack_bf(u32 pk) {
    return __uint_as_float(pk & 0xFFFF0000u) + __uint_as_float(pk << 16);
}

// read 8 packed elems (32B, 2x ds_read_b128) -> hi / lo bf16x8 fragments
__device__ __forceinline__ void load_afrag(const u32* p, bf16x8& ah, bf16x8& al) {
    u32 q[8];
    *reinterpret_cast<float4*>(q)     = *reinterpret_cast<const float4*>(p);
    *reinterpret_cast<float4*>(q + 4) = *reinterpret_cast<const float4*>(p + 4);
    union { u32 u[4]; bf16x8 v; } H, L;
#pragma unroll
    for (int j = 0; j < 4; j++) {
        H.u[j] = __builtin_amdgcn_perm(q[2 * j + 1], q[2 * j], 0x07060302u);
        L.u[j] = __builtin_amdgcn_perm(q[2 * j + 1], q[2 * j], 0x05040100u);
    }
    ah = H.v; al = L.v;
}

__global__ __launch_bounds__(256) void k_zero() {
    int i = blockIdx.x * 256 + threadIdx.x;
    if (i < NN) g_cnt[i] = 0;
}

// --- relnorm[r] = l2norm(rel_emb[r]); atab[t][r] = relnorm[r].attn_t ---
__global__ __launch_bounds__(256) void k_prep_rel(
    const float* __restrict__ rel_emb, const float* __restrict__ attn_e,
    const float* __restrict__ attn_r) {
    int wave = threadIdx.x >> 6, lane = threadIdx.x & 63;
    int r = blockIdx.x * 4 + wave;
    if (r >= NR) return;
    float2 v = *(const float2*)(rel_emb + r * FF + 2 * lane);
    float ss = wsum64(v.x * v.x + v.y * v.y);
    float inv = 1.f / fmaxf(sqrtf(ss), NEPS);
    float rn0 = v.x * inv, rn1 = v.y * inv;
    *(float2*)(g_relnorm + r * FF + 2 * lane) = make_float2(rn0, rn1);
#pragma unroll
    for (int t = 0; t < 4; t++) {
        const float* av = ((t < 2) ? attn_e : attn_r) + (t & 1) * FF + 2 * lane;
        float d = wsum64(rn0 * av[0] + rn1 * av[1]);
        if (lane == 0) g_atab[t * NR + r] = d;
    }
}

// --- split-bf16 proxy tables: l2n rows ([d][p][k]) and raw transpose ([d][f][p]) ---
__global__ __launch_bounds__(256) void k_prep_proxy(
    const float* __restrict__ proxy_e, const float* __restrict__ proxy_r) {
    int wave = threadIdx.x >> 6, lane = threadIdx.x & 63;
    int row = blockIdx.x * 4 + wave;  // 0..127
    if (row >= 2 * PP) return;
    int d = row >> 6, p = row & 63;
    const float* pr = ((d == 0) ? proxy_e : proxy_r) + p * FDIM;
    float v[6];
    float ss = 0.f;
#pragma unroll
    for (int j = 0; j < 6; j++) {
        v[j] = pr[lane + 64 * j];
        ss += v[j] * v[j];
    }
    ss = wsum64(ss);
    float inv = 1.f / fmaxf(sqrtf(ss), NEPS);
#pragma unroll
    for (int j = 0; j < 6; j++) {
        int k = lane + 64 * j;
        u32 pn = pack_bf(v[j] * inv);
        g_pxn_hi[(d * PP + p) * FDIM + k] = (u16)(pn >> 16);
        g_pxn_lo[(d * PP + p) * FDIM + k] = (u16)(pn & 0xFFFFu);
        u32 pt = pack_bf(v[j]);
        g_pxT_hi[(d * FDIM + k) * PP + p] = (u16)(pt >> 16);
        g_pxT_lo[(d * FDIM + k) * PP + p] = (u16)(pt & 0xFFFFu);
    }
}

// --- split-bf16 gate weights, transposed: wt[d][f][k] = W_d[k][f] ---
__global__ __launch_bounds__(256) void k_prep_wt(
    const float* __restrict__ gate_e, const float* __restrict__ gate_r) {
    int idx = blockIdx.x * 256 + threadIdx.x;
    if (idx >= 2 * FDIM * FDIM) return;
    int d = idx / (FDIM * FDIM);
    int rem = idx - d * (FDIM * FDIM);
    int k = rem / FDIM;
    int f = rem - k * FDIM;          // consecutive lanes -> consecutive f: coalesced read
    float wv = (d ? gate_r : gate_e)[k * FDIM + f];
    u32 pk = pack_bf(wv);
    g_wt_hi[(d * FDIM + f) * FDIM + k] = (u16)(pk >> 16);
    g_wt_lo[(d * FDIM + f) * FDIM + k] = (u16)(pk & 0xFFFFu);
}

__global__ __launch_bounds__(256) void k_count(const int* __restrict__ dst) {
    int e = blockIdx.x * 256 + threadIdx.x;
    if (e < NE) atomicAdd(&g_cnt[dst[e]], 1);
}

// single-block chunked Hillis-Steele exclusive scan; also rezeros cnt
__global__ __launch_bounds__(1024) void k_scan() {
    __shared__ int s[1024];
    __shared__ int carry;
    int tid = threadIdx.x;
    if (tid == 0) carry = 0;
    __syncthreads();
    for (int base = 0; base < NN; base += 1024) {
        int i = base + tid;
        int v = (i < NN) ? g_cnt[i] : 0;
        s[tid] = v;
        __syncthreads();
        for (int off = 1; off < 1024; off <<= 1) {
            int t = (tid >= off) ? s[tid - off] : 0;
            __syncthreads();
            s[tid] += t;
            __syncthreads();
        }
        int incl = s[tid];
        int c = carry;
        if (i < NN) {
            g_rowptr[i] = c + incl - v;
            g_cnt[i] = 0;
        }
        __syncthreads();
        if (tid == 1023) carry = c + s[1023];
        __syncthreads();
    }
    if (tid == 0) g_rowptr[NN] = carry;  // == NE
}

__global__ __launch_bounds__(256) void k_fill(
    const int* __restrict__ src, const int* __restrict__ dst,
    const int* __restrict__ rel) {
    int e = blockIdx.x * 256 + threadIdx.x;
    if (e >= NE) return;
    int d = dst[e];
    int pos = atomicAdd(&g_cnt[d], 1);
    g_csr[g_rowptr[d] + pos] = ((u32)src[e] << 16) | (u32)rel[e];
}

// --- initial features: tanh(mean over incoming edges), both duals ---
__global__ __launch_bounds__(256) void k_init(
    const float* __restrict__ ent_emb, const float* __restrict__ rel_emb,
    float* __restrict__ out) {
    int wave = threadIdx.x >> 6, lane = threadIdx.x & 63;
    int n = blockIdx.x * 4 + wave;
    if (n >= NN) return;
    int s0 = g_rowptr[n], s1 = g_rowptr[n + 1];
    float ae0 = 0, ae1 = 0, ar0 = 0, ar1 = 0;
    for (int idx = s0; idx < s1; idx++) {
        u32 pk = g_csr[idx];
        int s = __builtin_amdgcn_readfirstlane((int)(pk >> 16));
        int r = __builtin_amdgcn_readfirstlane((int)(pk & 0xFFFFu));
        float2 ue = *(const float2*)(ent_emb + s * FF + 2 * lane);
        float2 ur = *(const float2*)(rel_emb + r * FF + 2 * lane);
        ae0 += ue.x; ae1 += ue.y;
        ar0 += ur.x; ar1 += ur.y;
    }
    float invd = 1.f / (float)max(s1 - s0, 1);
    *(float2*)(out + n * OD + 2 * lane) =
        make_float2(tanhf(ae0 * invd), tanhf(ae1 * invd));
    *(float2*)(out + n * OD + FDIM + 2 * lane) =
        make_float2(tanhf(ar0 * invd), tanhf(ar1 * invd));
}

// --- one message-passing layer: wave per node, edge-softmax + Householder ---
__global__ __launch_bounds__(256) void k_layer(float* buf, int layer) {
    int wave = threadIdx.x >> 6, lane = threadIdx.x & 63;
    int n = blockIdx.x * 4 + wave;
    if (n >= NN) return;
    int dual = blockIdx.y;
    int base_in = dual * FDIM + layer * FF;
    int base_out = base_in + FF;
    int t = dual * 2 + layer;
    const float* atab = g_atab + t * NR;
    int s0 = g_rowptr[n], s1 = g_rowptr[n + 1];
    float* outp = buf + n * OD + base_out + 2 * lane;
    if (s1 == s0) {
        *(float2*)outp = make_float2(0.f, 0.f);
        return;
    }
    float am = -1e30f;
    for (int idx = s0 + lane; idx < s1; idx += 64)
        am = fmaxf(am, atab[g_csr[idx] & 0xFFFFu]);
    am = wmax64(am);
    float acc0 = 0.f, acc1 = 0.f, ws = 0.f;
    for (int idx = s0; idx < s1; idx++) {
        u32 pk = g_csr[idx];
        int s = __builtin_amdgcn_readfirstlane((int)(pk >> 16));
        int r = __builtin_amdgcn_readfirstlane((int)(pk & 0xFFFFu));
        float2 h = *(const float2*)(buf + s * OD + base_in + 2 * lane);
        float2 rn = *(const float2*)(g_relnorm + r * FF + 2 * lane);
        float dot = wsum64(h.x * rn.x + h.y * rn.y);
        float w = expf(atab[r] - am);
        ws += w;
        acc0 += w * (h.x - 2.f * dot * rn.x);
        acc1 += w * (h.y - 2.f * dot * rn.y);
    }
    float inv = 1.f / ws;
    *(float2*)outp = make_float2(tanhf(acc0 * inv), tanhf(acc1 * inv));
}

// --- fused proxy attention + gate, MFMA version: 16 nodes/block, y = dual ---
// phases: stage o -> invn -> pack o -> logits(MFMA) -> softmax -> pack att ->
//         pf = o - att@proxy (MFMA, repacked in place) -> gate GEMM (MFMA) ->
//         epilogue out = g*o + (1-g)*pf.
// LDS 28.6 KB -> 5 blocks/CU (same as previous fp32 version).
__global__ __launch_bounds__(256) void k_pg(
    float* out, const float* __restrict__ bias_e,
    const float* __restrict__ bias_r) {
    __shared__ __attribute__((aligned(16))) u32 o_pk[16 * FSTR];   // fp32 bits, then packed
    __shared__ __attribute__((aligned(16))) u32 att_pk[16 * ASTR]; // fp32 bits, then packed
    __shared__ float invn_s[16];
    int tid = threadIdx.x;
    int lane = tid & 63, w = tid >> 6;
    int c = lane & 15, kg = lane >> 4;   // MFMA fragment coords
    int n0 = blockIdx.x * 16, dual = blockIdx.y;
    int dual_off = dual * FDIM;
    const float* bias = dual ? bias_r : bias_e;
    const u16* wt_h = g_wt_hi + dual * (FDIM * FDIM);
    const u16* wt_l = g_wt_lo + dual * (FDIM * FDIM);
    const u16* pn_h = g_pxn_hi + dual * (PP * FDIM);
    const u16* pn_l = g_pxn_lo + dual * (PP * FDIM);
    const u16* pt_h = g_pxT_hi + dual * (FDIM * PP);
    const u16* pt_l = g_pxT_lo + dual * (FDIM * PP);

    // ---- stage o (fp32 bits) ----
    for (int i4 = tid; i4 < 16 * (FDIM / 4); i4 += 256) {
        int n = i4 / (FDIM / 4), c4 = i4 - n * (FDIM / 4);
        float4 u = *(const float4*)(out + (n0 + n) * OD + dual_off + 4 * c4);
        u32* dp = o_pk + n * FSTR + 4 * c4;
        dp[0] = __float_as_uint(u.x); dp[1] = __float_as_uint(u.y);
        dp[2] = __float_as_uint(u.z); dp[3] = __float_as_uint(u.w);
    }
    __syncthreads();
    // ---- 1/||o|| per node (wave w owns nodes w+4j) ----
#pragma unroll
    for (int j = 0; j < 4; j++) {
        int n = w + 4 * j;
        float ss = 0.f;
#pragma unroll
        for (int q = 0; q < 6; q++) {
            float v = __uint_as_float(o_pk[n * FSTR + lane + 64 * q]);
            ss += v * v;
        }
        ss = wsum64(ss);
        if (lane == 0) invn_s[n] = 1.f / fmaxf(sqrtf(ss), NEPS);
    }
    __syncthreads();
    // ---- pack o -> (hi|lo) in place ----
    for (int i4 = tid; i4 < 16 * (FDIM / 4); i4 += 256) {
        int n = i4 / (FDIM / 4), c4 = i4 - n * (FDIM / 4);
        u32* p = o_pk + n * FSTR + 4 * c4;
        u32 a0 = pack_bf(__uint_as_float(p[0]));
        u32 a1 = pack_bf(__uint_as_float(p[1]));
        u32 a2 = pack_bf(__uint_as_float(p[2]));
        u32 a3 = pack_bf(__uint_as_float(p[3]));
        p[0] = a0; p[1] = a1; p[2] = a2; p[3] = a3;
    }
    __syncthreads();
    // ---- logits = (o @ l2n(proxy)^T) * invn; wave w -> p in [16w,16w+16) ----
    {
        f32x4 lacc = {0.f, 0.f, 0.f, 0.f};
        const u16* bh_p = pn_h + (16 * w + c) * FDIM;
        const u16* bl_p = pn_l + (16 * w + c) * FDIM;
        const u32* ap = o_pk + c * FSTR;
        for (int ks = 0; ks < 12; ks++) {
            int kb = 32 * ks + 8 * kg;
            bf16x8 ah, al;
            load_afrag(ap + kb, ah, al);
            bf16x8 bh = *(const bf16x8*)(bh_p + kb);
            bf16x8 bl = *(const bf16x8*)(bl_p + kb);
            lacc = __builtin_amdgcn_mfma_f32_16x16x32_bf16(ah, bh, lacc, 0, 0, 0);
            lacc = __builtin_amdgcn_mfma_f32_16x16x32_bf16(al, bh, lacc, 0, 0, 0);
            lacc = __builtin_amdgcn_mfma_f32_16x16x32_bf16(ah, bl, lacc, 0, 0, 0);
        }
#pragma unroll
        for (int i = 0; i < 4; i++) {
            int n = 4 * kg + i;
            att_pk[n * ASTR + 16 * w + c] = __float_as_uint(lacc[i] * invn_s[n]);
        }
    }
    __syncthreads();
    // ---- softmax over P=64 per node ----
#pragma unroll
    for (int j = 0; j < 4; j++) {
        int n = w + 4 * j;
        float l = __uint_as_float(att_pk[n * ASTR + lane]);
        float m = wmax64(l);
        float e = expf(l - m);
        float s = wsum64(e);
        att_pk[n * ASTR + lane] = __float_as_uint(e / s);
    }
    __syncthreads();
    // ---- pack att in place ----
    for (int i = tid; i < 16 * PP; i += 256) {
        int n = i >> 6, p = i & 63;
        u32* q = att_pk + n * ASTR + p;
        *q = pack_bf(__uint_as_float(*q));
    }
    __syncthreads();
    // ---- pf = o - att @ proxy (K=64); repack pf over o in place ----
    {
        f32x4 pacc[6];
#pragma unroll
        for (int t = 0; t < 6; t++) pacc[t] = (f32x4){0.f, 0.f, 0.f, 0.f};
        bf16x8 aah0, aal0, aah1, aal1;
        load_afrag(att_pk + c * ASTR + 8 * kg, aah0, aal0);
        load_afrag(att_pk + c * ASTR + 32 + 8 * kg, aah1, aal1);
#pragma unroll
        for (int t = 0; t < 6; t++) {
            int f = 96 * w + 16 * t + c;
            const u16* bh0 = pt_h + f * PP;
            const u16* bl0 = pt_l + f * PP;
            int kb0 = 8 * kg, kb1 = 32 + 8 * kg;
            bf16x8 b0h = *(const bf16x8*)(bh0 + kb0);
            bf16x8 b0l = *(const bf16x8*)(bl0 + kb0);
            bf16x8 b1h = *(const bf16x8*)(bh0 + kb1);
            bf16x8 b1l = *(const bf16x8*)(bl0 + kb1);
            pacc[t] = __builtin_amdgcn_mfma_f32_16x16x32_bf16(aah0, b0h, pacc[t], 0, 0, 0);
            pacc[t] = __builtin_amdgcn_mfma_f32_16x16x32_bf16(aal0, b0h, pacc[t], 0, 0, 0);
            pacc[t] = __builtin_amdgcn_mfma_f32_16x16x32_bf16(aah0, b0l, pacc[t], 0, 0, 0);
            pacc[t] = __builtin_amdgcn_mfma_f32_16x16x32_bf16(aah1, b1h, pacc[t], 0, 0, 0);
            pacc[t] = __builtin_amdgcn_mfma_f32_16x16x32_bf16(aal1, b1h, pacc[t], 0, 0, 0);
            pacc[t] = __builtin_amdgcn_mfma_f32_16x16x32_bf16(aah1, b1l, pacc[t], 0, 0, 0);
        }
#pragma unroll
        for (int t = 0; t < 6; t++) {
            int f = 96 * w + 16 * t + c;
#pragma unroll
            for (int i = 0; i < 4; i++) {
                int n = 4 * kg + i;
                u32 pk = o_pk[n * FSTR + f];
                o_pk[n * FSTR + f] = pack_bf(unpack_bf(pk) - pacc[t][i]);
            }
        }
    }
    __syncthreads();
    // ---- gate GEMM: lin = pf @ W; wave w -> f-slab [96w, 96w+96) ----
    f32x4 gacc[6];
#pragma unroll
    for (int t = 0; t < 6; t++) gacc[t] = (f32x4){0.f, 0.f, 0.f, 0.f};
    {
        const u32* ap = o_pk + c * FSTR;
        for (int ks = 0; ks < 12; ks++) {
            int kb = 32 * ks + 8 * kg;
            bf16x8 ah, al;
            load_afrag(ap + kb, ah, al);
#pragma unroll
            for (int t = 0; t < 6; t++) {
                int f = 96 * w + 16 * t + c;
                bf16x8 bh = *(const bf16x8*)(wt_h + f * FDIM + kb);
                bf16x8 bl = *(const bf16x8*)(wt_l + f * FDIM + kb);
                gacc[t] = __builtin_amdgcn_mfma_f32_16x16x32_bf16(ah, bh, gacc[t], 0, 0, 0);
                gacc[t] = __builtin_amdgcn_mfma_f32_16x16x32_bf16(al, bh, gacc[t], 0, 0, 0);
                gacc[t] = __builtin_amdgcn_mfma_f32_16x16x32_bf16(ah, bl, gacc[t], 0, 0, 0);
            }
        }
    }
    // ---- epilogue: gt = sigmoid(lin + bias); out = gt*o + (1-gt)*pf ----
#pragma unroll
    for (int t = 0; t < 6; t++) {
        int fcol = 96 * w + 16 * t + c;
        float b = bias[fcol];
#pragma unroll
        for (int i = 0; i < 4; i++) {
            int n = 4 * kg + i;
            float lin = gacc[t][i] + b;
            float gt = 1.f / (1.f + expf(-lin));
            float pv = unpack_bf(o_pk[n * FSTR + fcol]);
            float* op = out + (n0 + n) * OD + dual_off + fcol;
            float o = *op;
            *op = gt * o + (1.f - gt) * pv;
        }
    }
}

extern "C" void kernel_launch(void* const* d_in, const int* in_sizes, int n_in,
                              void* d_out, int out_size, void* d_ws, size_t ws_size,
                              hipStream_t stream) {
    const float* ent_emb = (const float*)d_in[0];
    const float* rel_emb = (const float*)d_in[1];
    const int* e_src     = (const int*)d_in[2];
    const int* e_dst     = (const int*)d_in[3];
    const int* e_rel     = (const int*)d_in[4];
    const float* attn_e  = (const float*)d_in[5];
    const float* gate_e  = (const float*)d_in[6];
    const float* proxy_e = (const float*)d_in[7];
    const float* bias_e  = (const float*)d_in[8];
    const float* attn_r  = (const float*)d_in[9];
    const float* gate_r  = (const float*)d_in[10];
    const float* proxy_r = (const float*)d_in[11];
    const float* bias_r  = (const float*)d_in[12];
    float* out = (float*)d_out;
    (void)d_ws; (void)ws_size; (void)in_sizes; (void)n_in; (void)out_size;

    k_zero<<<(NN + 255) / 256, 256, 0, stream>>>();
    k_prep_rel<<<NR / 4, 256, 0, stream>>>(rel_emb, attn_e, attn_r);
    k_prep_proxy<<<32, 256, 0, stream>>>(proxy_e, proxy_r);
    k_prep_wt<<<(2 * FDIM * FDIM + 255) / 256, 256, 0, stream>>>(gate_e, gate_r);
    k_count<<<(NE + 255) / 256, 256, 0, stream>>>(e_dst);
    k_scan<<<1, 1024, 0, stream>>>();
    k_fill<<<(NE + 255) / 256, 256, 0, stream>>>(e_src, e_dst, e_rel);
    k_init<<<NN / 4, 256, 0, stream>>>(ent_emb, rel_emb, out);
    k_layer<<<dim3(NN / 4, 2), 256, 0, stream>>>(out, 0);
    k_layer<<<dim3(NN / 4, 2), 256, 0, stream>>>(out, 1);
    k_pg<<<dim3(NN / 16, 2), 256, 0, stream>>>(out, bias_e, bias_r);
}

// Round 2
// 1350.748 us; speedup vs baseline: 1.2603x; 1.1549x over previous
//
#include <hip/hip_runtime.h>
#include <math.h>

// ---------------------------------------------------------------------------
// overAll_37606733644133 : relational GNN (2-layer Householder-reflection
// message passing with edge softmax) + proxy attention + gated mixing.
//
// k_pg v3: split-bf16 MFMA (3-term) with latency-oriented restructure:
//  - 32 nodes/block (two 16-row M-tiles) -> each B fragment feeds 6 MFMAs,
//    W streamed from L2 once per 32 nodes (was 16).
//  - gate GEMM: all 12 B fragments loaded into named register arrays per
//    K-step, ks-loop unrolled x2 -> compiler double-buffers L2 loads under
//    the 36-MFMA cluster. __launch_bounds__(256,2) frees VGPR budget
//    (LDS 58.5KB already caps at 2 blocks/CU).
//  - fused stage+sumsq+pack and softmax+pack phases (4 syncs total).
//  - epilogue reconstructs o = pf + pacc from registers (no global re-read).
// ---------------------------------------------------------------------------

#define NN    50000
#define NE    800000
#define NR    2000
#define FF    128
#define FDIM  384
#define OD    768     // output row stride (2 duals x 384)
#define PP    64
#define NEPS  1e-12f
#define NPB   32      // nodes per k_pg block
#define FSTR  388     // LDS row stride (u32) for o/pf tile: 388%32=4 -> 2-way (free)
#define ASTR  68      // LDS row stride (u32) for att tile:  68%32=4 -> 2-way (free)

typedef unsigned int u32;
typedef unsigned short u16;
typedef __attribute__((ext_vector_type(8))) short bf16x8;   // 8 bf16 (4 VGPRs)
typedef __attribute__((ext_vector_type(4))) float f32x4;

// ---- static device scratch ------------------------------------------------
__device__ int   g_rowptr[NN + 1];
__device__ int   g_cnt[NN];
__device__ u32   g_csr[NE];               // (src<<16) | rel
__device__ float g_relnorm[NR * FF];
__device__ float g_atab[4 * NR];          // 0=ent-l0,1=ent-l1,2=rel-l0,3=rel-l1
// split-bf16 B-operands, all n-major / k-contiguous:
__device__ __attribute__((aligned(16))) u16 g_wt_hi[2 * FDIM * FDIM];  // [d][f][k] = W_d[k][f]
__device__ __attribute__((aligned(16))) u16 g_wt_lo[2 * FDIM * FDIM];
__device__ __attribute__((aligned(16))) u16 g_pxn_hi[2 * PP * FDIM];   // [d][p][k] = l2n(proxy_d[p])[k]
__device__ __attribute__((aligned(16))) u16 g_pxn_lo[2 * PP * FDIM];
__device__ __attribute__((aligned(16))) u16 g_pxT_hi[2 * FDIM * PP];   // [d][f][p] = proxy_d[p][f]
__device__ __attribute__((aligned(16))) u16 g_pxT_lo[2 * FDIM * PP];

__device__ __forceinline__ float wsum64(float v) {
#pragma unroll
    for (int m = 32; m > 0; m >>= 1) v += __shfl_xor(v, m, 64);
    return v;
}
__device__ __forceinline__ float wmax64(float v) {
#pragma unroll
    for (int m = 32; m > 0; m >>= 1) v = fmaxf(v, __shfl_xor(v, m, 64));
    return v;
}

// fp32 -> (bf16_hi << 16) | bf16_lo, both RNE; hi+lo reconstructs to ~2^-16 rel
__device__ __forceinline__ u32 pack_bf(float f) {
    u32 x = __float_as_uint(f);
    u32 hr = (x + 0x7FFFu + ((x >> 16) & 1u)) & 0xFFFF0000u;
    float res = f - __uint_as_float(hr);
    u32 y = __float_as_uint(res);
    u32 lr = (y + 0x7FFFu + ((y >> 16) & 1u)) >> 16;
    return hr | lr;
}
__device__ __forceinline__ float unpack_bf(u32 pk) {
    return __uint_as_float(pk & 0xFFFF0000u) + __uint_as_float(pk << 16);
}

// read 8 packed elems (32B, 2x ds_read_b128) -> hi / lo bf16x8 fragments
__device__ __forceinline__ void load_afrag(const u32* p, bf16x8& ah, bf16x8& al) {
    u32 q[8];
    *reinterpret_cast<float4*>(q)     = *reinterpret_cast<const float4*>(p);
    *reinterpret_cast<float4*>(q + 4) = *reinterpret_cast<const float4*>(p + 4);
    union { u32 u[4]; bf16x8 v; } H, L;
#pragma unroll
    for (int j = 0; j < 4; j++) {
        H.u[j] = __builtin_amdgcn_perm(q[2 * j + 1], q[2 * j], 0x07060302u);
        L.u[j] = __builtin_amdgcn_perm(q[2 * j + 1], q[2 * j], 0x05040100u);
    }
    ah = H.v; al = L.v;
}

__global__ __launch_bounds__(256) void k_zero() {
    int i = blockIdx.x * 256 + threadIdx.x;
    if (i < NN) g_cnt[i] = 0;
}

// --- relnorm[r] = l2norm(rel_emb[r]); atab[t][r] = relnorm[r].attn_t ---
__global__ __launch_bounds__(256) void k_prep_rel(
    const float* __restrict__ rel_emb, const float* __restrict__ attn_e,
    const float* __restrict__ attn_r) {
    int wave = threadIdx.x >> 6, lane = threadIdx.x & 63;
    int r = blockIdx.x * 4 + wave;
    if (r >= NR) return;
    float2 v = *(const float2*)(rel_emb + r * FF + 2 * lane);
    float ss = wsum64(v.x * v.x + v.y * v.y);
    float inv = 1.f / fmaxf(sqrtf(ss), NEPS);
    float rn0 = v.x * inv, rn1 = v.y * inv;
    *(float2*)(g_relnorm + r * FF + 2 * lane) = make_float2(rn0, rn1);
#pragma unroll
    for (int t = 0; t < 4; t++) {
        const float* av = ((t < 2) ? attn_e : attn_r) + (t & 1) * FF + 2 * lane;
        float d = wsum64(rn0 * av[0] + rn1 * av[1]);
        if (lane == 0) g_atab[t * NR + r] = d;
    }
}

// --- split-bf16 proxy tables: l2n rows ([d][p][k]) and raw transpose ([d][f][p]) ---
__global__ __launch_bounds__(256) void k_prep_proxy(
    const float* __restrict__ proxy_e, const float* __restrict__ proxy_r) {
    int wave = threadIdx.x >> 6, lane = threadIdx.x & 63;
    int row = blockIdx.x * 4 + wave;  // 0..127
    if (row >= 2 * PP) return;
    int d = row >> 6, p = row & 63;
    const float* pr = ((d == 0) ? proxy_e : proxy_r) + p * FDIM;
    float v[6];
    float ss = 0.f;
#pragma unroll
    for (int j = 0; j < 6; j++) {
        v[j] = pr[lane + 64 * j];
        ss += v[j] * v[j];
    }
    ss = wsum64(ss);
    float inv = 1.f / fmaxf(sqrtf(ss), NEPS);
#pragma unroll
    for (int j = 0; j < 6; j++) {
        int k = lane + 64 * j;
        u32 pn = pack_bf(v[j] * inv);
        g_pxn_hi[(d * PP + p) * FDIM + k] = (u16)(pn >> 16);
        g_pxn_lo[(d * PP + p) * FDIM + k] = (u16)(pn & 0xFFFFu);
        u32 pt = pack_bf(v[j]);
        g_pxT_hi[(d * FDIM + k) * PP + p] = (u16)(pt >> 16);
        g_pxT_lo[(d * FDIM + k) * PP + p] = (u16)(pt & 0xFFFFu);
    }
}

// --- split-bf16 gate weights, transposed: wt[d][f][k] = W_d[k][f] ---
__global__ __launch_bounds__(256) void k_prep_wt(
    const float* __restrict__ gate_e, const float* __restrict__ gate_r) {
    int idx = blockIdx.x * 256 + threadIdx.x;
    if (idx >= 2 * FDIM * FDIM) return;
    int d = idx / (FDIM * FDIM);
    int rem = idx - d * (FDIM * FDIM);
    int k = rem / FDIM;
    int f = rem - k * FDIM;          // consecutive lanes -> consecutive f: coalesced read
    float wv = (d ? gate_r : gate_e)[k * FDIM + f];
    u32 pk = pack_bf(wv);
    g_wt_hi[(d * FDIM + f) * FDIM + k] = (u16)(pk >> 16);
    g_wt_lo[(d * FDIM + f) * FDIM + k] = (u16)(pk & 0xFFFFu);
}

__global__ __launch_bounds__(256) void k_count(const int* __restrict__ dst) {
    int e = blockIdx.x * 256 + threadIdx.x;
    if (e < NE) atomicAdd(&g_cnt[dst[e]], 1);
}

// single-block chunked Hillis-Steele exclusive scan; also rezeros cnt
__global__ __launch_bounds__(1024) void k_scan() {
    __shared__ int s[1024];
    __shared__ int carry;
    int tid = threadIdx.x;
    if (tid == 0) carry = 0;
    __syncthreads();
    for (int base = 0; base < NN; base += 1024) {
        int i = base + tid;
        int v = (i < NN) ? g_cnt[i] : 0;
        s[tid] = v;
        __syncthreads();
        for (int off = 1; off < 1024; off <<= 1) {
            int t = (tid >= off) ? s[tid - off] : 0;
            __syncthreads();
            s[tid] += t;
            __syncthreads();
        }
        int incl = s[tid];
        int c = carry;
        if (i < NN) {
            g_rowptr[i] = c + incl - v;
            g_cnt[i] = 0;
        }
        __syncthreads();
        if (tid == 1023) carry = c + s[1023];
        __syncthreads();
    }
    if (tid == 0) g_rowptr[NN] = carry;  // == NE
}

__global__ __launch_bounds__(256) void k_fill(
    const int* __restrict__ src, const int* __restrict__ dst,
    const int* __restrict__ rel) {
    int e = blockIdx.x * 256 + threadIdx.x;
    if (e >= NE) return;
    int d = dst[e];
    int pos = atomicAdd(&g_cnt[d], 1);
    g_csr[g_rowptr[d] + pos] = ((u32)src[e] << 16) | (u32)rel[e];
}

// --- initial features: tanh(mean over incoming edges), both duals ---
__global__ __launch_bounds__(256) void k_init(
    const float* __restrict__ ent_emb, const float* __restrict__ rel_emb,
    float* __restrict__ out) {
    int wave = threadIdx.x >> 6, lane = threadIdx.x & 63;
    int n = blockIdx.x * 4 + wave;
    if (n >= NN) return;
    int s0 = g_rowptr[n], s1 = g_rowptr[n + 1];
    float ae0 = 0, ae1 = 0, ar0 = 0, ar1 = 0;
    for (int idx = s0; idx < s1; idx++) {
        u32 pk = g_csr[idx];
        int s = __builtin_amdgcn_readfirstlane((int)(pk >> 16));
        int r = __builtin_amdgcn_readfirstlane((int)(pk & 0xFFFFu));
        float2 ue = *(const float2*)(ent_emb + s * FF + 2 * lane);
        float2 ur = *(const float2*)(rel_emb + r * FF + 2 * lane);
        ae0 += ue.x; ae1 += ue.y;
        ar0 += ur.x; ar1 += ur.y;
    }
    float invd = 1.f / (float)max(s1 - s0, 1);
    *(float2*)(out + n * OD + 2 * lane) =
        make_float2(tanhf(ae0 * invd), tanhf(ae1 * invd));
    *(float2*)(out + n * OD + FDIM + 2 * lane) =
        make_float2(tanhf(ar0 * invd), tanhf(ar1 * invd));
}

// --- one message-passing layer: wave per node, edge-softmax + Householder ---
__global__ __launch_bounds__(256) void k_layer(float* buf, int layer) {
    int wave = threadIdx.x >> 6, lane = threadIdx.x & 63;
    int n = blockIdx.x * 4 + wave;
    if (n >= NN) return;
    int dual = blockIdx.y;
    int base_in = dual * FDIM + layer * FF;
    int base_out = base_in + FF;
    int t = dual * 2 + layer;
    const float* atab = g_atab + t * NR;
    int s0 = g_rowptr[n], s1 = g_rowptr[n + 1];
    float* outp = buf + n * OD + base_out + 2 * lane;
    if (s1 == s0) {
        *(float2*)outp = make_float2(0.f, 0.f);
        return;
    }
    float am = -1e30f;
    for (int idx = s0 + lane; idx < s1; idx += 64)
        am = fmaxf(am, atab[g_csr[idx] & 0xFFFFu]);
    am = wmax64(am);
    float acc0 = 0.f, acc1 = 0.f, ws = 0.f;
    for (int idx = s0; idx < s1; idx++) {
        u32 pk = g_csr[idx];
        int s = __builtin_amdgcn_readfirstlane((int)(pk >> 16));
        int r = __builtin_amdgcn_readfirstlane((int)(pk & 0xFFFFu));
        float2 h = *(const float2*)(buf + s * OD + base_in + 2 * lane);
        float2 rn = *(const float2*)(g_relnorm + r * FF + 2 * lane);
        float dot = wsum64(h.x * rn.x + h.y * rn.y);
        float w = expf(atab[r] - am);
        ws += w;
        acc0 += w * (h.x - 2.f * dot * rn.x);
        acc1 += w * (h.y - 2.f * dot * rn.y);
    }
    float inv = 1.f / ws;
    *(float2*)outp = make_float2(tanhf(acc0 * inv), tanhf(acc1 * inv));
}

// --- fused proxy attention + gate, MFMA v3: 32 nodes/block, y = dual ---
__global__ __launch_bounds__(256, 2) void k_pg(
    float* out, const float* __restrict__ bias_e,
    const float* __restrict__ bias_r) {
    __shared__ __attribute__((aligned(16))) u32 o_pk[NPB * FSTR];   // 49.7 KB
    __shared__ __attribute__((aligned(16))) u32 att_pk[NPB * ASTR]; // 8.7 KB
    __shared__ float invn_s[NPB];
    int tid = threadIdx.x;
    int lane = tid & 63, w = tid >> 6;
    int c = lane & 15, kg = lane >> 4;   // MFMA fragment coords
    int n0 = blockIdx.x * NPB, dual = blockIdx.y;
    int dual_off = dual * FDIM;
    const float* bias = dual ? bias_r : bias_e;
    const u16* wt_h = g_wt_hi + dual * (FDIM * FDIM);
    const u16* wt_l = g_wt_lo + dual * (FDIM * FDIM);
    const u16* pn_h = g_pxn_hi + dual * (PP * FDIM);
    const u16* pn_l = g_pxn_lo + dual * (PP * FDIM);
    const u16* pt_h = g_pxT_hi + dual * (FDIM * PP);
    const u16* pt_l = g_pxT_lo + dual * (FDIM * PP);

    // ---- phase 1: stage + sumsq + pack in one pass (wave w: rows w+4j) ----
#pragma unroll
    for (int j = 0; j < 8; j++) {
        int n = w + 4 * j;
        int gn = n0 + n;
        float2 v[3];
        if (gn < NN) {
            const float* rp = out + (size_t)gn * OD + dual_off;
#pragma unroll
            for (int q = 0; q < 3; q++) v[q] = *(const float2*)(rp + 2 * (lane + 64 * q));
        } else {
            v[0] = v[1] = v[2] = make_float2(0.f, 0.f);
        }
        float ss = 0.f;
#pragma unroll
        for (int q = 0; q < 3; q++) ss += v[q].x * v[q].x + v[q].y * v[q].y;
        ss = wsum64(ss);
        if (lane == 0) invn_s[n] = 1.f / fmaxf(sqrtf(ss), NEPS);
#pragma unroll
        for (int q = 0; q < 3; q++) {
            u32 p0 = pack_bf(v[q].x), p1 = pack_bf(v[q].y);
            uint2 pr; pr.x = p0; pr.y = p1;
            *(uint2*)(o_pk + n * FSTR + 2 * (lane + 64 * q)) = pr;
        }
    }
    __syncthreads();

    // ---- phase 2: logits = (o @ l2n(proxy)^T)*invn; wave w -> p-tile, both m ----
    {
        f32x4 lacc[2] = {{0.f,0.f,0.f,0.f},{0.f,0.f,0.f,0.f}};
        const u16* bh_p = pn_h + (16 * w + c) * FDIM;
        const u16* bl_p = pn_l + (16 * w + c) * FDIM;
#pragma unroll 2
        for (int ks = 0; ks < 12; ks++) {
            int kb = 32 * ks + 8 * kg;
            bf16x8 bh = *(const bf16x8*)(bh_p + kb);
            bf16x8 bl = *(const bf16x8*)(bl_p + kb);
#pragma unroll
            for (int m = 0; m < 2; m++) {
                bf16x8 ah, al;
                load_afrag(o_pk + (16 * m + c) * FSTR + kb, ah, al);
                lacc[m] = __builtin_amdgcn_mfma_f32_16x16x32_bf16(ah, bh, lacc[m], 0, 0, 0);
                lacc[m] = __builtin_amdgcn_mfma_f32_16x16x32_bf16(al, bh, lacc[m], 0, 0, 0);
                lacc[m] = __builtin_amdgcn_mfma_f32_16x16x32_bf16(ah, bl, lacc[m], 0, 0, 0);
            }
        }
#pragma unroll
        for (int m = 0; m < 2; m++)
#pragma unroll
            for (int i = 0; i < 4; i++) {
                int n = 16 * m + 4 * kg + i;
                att_pk[n * ASTR + 16 * w + c] = __float_as_uint(lacc[m][i] * invn_s[n]);
            }
    }
    __syncthreads();

    // ---- phase 3: softmax over P=64 + pack, one pass ----
#pragma unroll
    for (int j = 0; j < 8; j++) {
        int n = w + 4 * j;
        float l = __uint_as_float(att_pk[n * ASTR + lane]);
        float mx = wmax64(l);
        float e = expf(l - mx);
        float s = wsum64(e);
        att_pk[n * ASTR + lane] = pack_bf(e / s);
    }
    __syncthreads();

    // ---- phase 4: pf = o - att @ proxy (K=64); repack pf over o in place ----
    f32x4 pacc[2][6];
#pragma unroll
    for (int m = 0; m < 2; m++)
#pragma unroll
        for (int t = 0; t < 6; t++) pacc[m][t] = (f32x4){0.f, 0.f, 0.f, 0.f};
    {
        bf16x8 aah[2][2], aal[2][2];   // [m][k-half]
#pragma unroll
        for (int m = 0; m < 2; m++) {
            load_afrag(att_pk + (16 * m + c) * ASTR + 8 * kg, aah[m][0], aal[m][0]);
            load_afrag(att_pk + (16 * m + c) * ASTR + 32 + 8 * kg, aah[m][1], aal[m][1]);
        }
#pragma unroll
        for (int t = 0; t < 6; t++) {
            int f = 96 * w + 16 * t + c;
            const u16* bh0 = pt_h + f * PP;
            const u16* bl0 = pt_l + f * PP;
            bf16x8 b0h = *(const bf16x8*)(bh0 + 8 * kg);
            bf16x8 b0l = *(const bf16x8*)(bl0 + 8 * kg);
            bf16x8 b1h = *(const bf16x8*)(bh0 + 32 + 8 * kg);
            bf16x8 b1l = *(const bf16x8*)(bl0 + 32 + 8 * kg);
#pragma unroll
            for (int m = 0; m < 2; m++) {
                pacc[m][t] = __builtin_amdgcn_mfma_f32_16x16x32_bf16(aah[m][0], b0h, pacc[m][t], 0, 0, 0);
                pacc[m][t] = __builtin_amdgcn_mfma_f32_16x16x32_bf16(aal[m][0], b0h, pacc[m][t], 0, 0, 0);
                pacc[m][t] = __builtin_amdgcn_mfma_f32_16x16x32_bf16(aah[m][0], b0l, pacc[m][t], 0, 0, 0);
                pacc[m][t] = __builtin_amdgcn_mfma_f32_16x16x32_bf16(aah[m][1], b1h, pacc[m][t], 0, 0, 0);
                pacc[m][t] = __builtin_amdgcn_mfma_f32_16x16x32_bf16(aal[m][1], b1h, pacc[m][t], 0, 0, 0);
                pacc[m][t] = __builtin_amdgcn_mfma_f32_16x16x32_bf16(aah[m][1], b1l, pacc[m][t], 0, 0, 0);
            }
        }
        // pf write-back (packed); each thread owns its (n,f) cells
#pragma unroll
        for (int t = 0; t < 6; t++) {
            int f = 96 * w + 16 * t + c;
#pragma unroll
            for (int m = 0; m < 2; m++)
#pragma unroll
                for (int i = 0; i < 4; i++) {
                    int n = 16 * m + 4 * kg + i;
                    u32 pk = o_pk[n * FSTR + f];
                    o_pk[n * FSTR + f] = pack_bf(unpack_bf(pk) - pacc[m][t][i]);
                }
        }
    }
    __syncthreads();

    // ---- phase 5: gate GEMM lin = pf @ W, register-pipelined B loads ----
    f32x4 gacc[2][6];
#pragma unroll
    for (int m = 0; m < 2; m++)
#pragma unroll
        for (int t = 0; t < 6; t++) gacc[m][t] = (f32x4){0.f, 0.f, 0.f, 0.f};
    {
        const u16* wtw_h = wt_h + (96 * w + c) * FDIM;
        const u16* wtw_l = wt_l + (96 * w + c) * FDIM;
#pragma unroll 2
        for (int ks = 0; ks < 12; ks++) {
            int kb = 32 * ks + 8 * kg;
            bf16x8 bhv[6], blv[6];
#pragma unroll
            for (int t = 0; t < 6; t++) {
                bhv[t] = *(const bf16x8*)(wtw_h + t * 16 * FDIM + kb);
                blv[t] = *(const bf16x8*)(wtw_l + t * 16 * FDIM + kb);
            }
            bf16x8 ah[2], al[2];
#pragma unroll
            for (int m = 0; m < 2; m++)
                load_afrag(o_pk + (16 * m + c) * FSTR + kb, ah[m], al[m]);
#pragma unroll
            for (int t = 0; t < 6; t++)
#pragma unroll
                for (int m = 0; m < 2; m++) {
                    gacc[m][t] = __builtin_amdgcn_mfma_f32_16x16x32_bf16(ah[m], bhv[t], gacc[m][t], 0, 0, 0);
                    gacc[m][t] = __builtin_amdgcn_mfma_f32_16x16x32_bf16(al[m], bhv[t], gacc[m][t], 0, 0, 0);
                    gacc[m][t] = __builtin_amdgcn_mfma_f32_16x16x32_bf16(ah[m], blv[t], gacc[m][t], 0, 0, 0);
                }
        }
    }

    // ---- epilogue: gt = sigmoid(lin+bias); o = pf + pacc; out = gt*o + (1-gt)*pf ----
#pragma unroll
    for (int t = 0; t < 6; t++) {
        int fcol = 96 * w + 16 * t + c;
        float b = bias[fcol];
#pragma unroll
        for (int m = 0; m < 2; m++)
#pragma unroll
            for (int i = 0; i < 4; i++) {
                int n = 16 * m + 4 * kg + i;
                int gn = n0 + n;
                if (gn < NN) {
                    float lin = gacc[m][t][i] + b;
                    float gt = 1.f / (1.f + expf(-lin));
                    float pv = unpack_bf(o_pk[n * FSTR + fcol]);
                    float ov = pv + pacc[m][t][i];
                    out[(size_t)gn * OD + dual_off + fcol] = gt * ov + (1.f - gt) * pv;
                }
            }
    }
}

extern "C" void kernel_launch(void* const* d_in, const int* in_sizes, int n_in,
                              void* d_out, int out_size, void* d_ws, size_t ws_size,
                              hipStream_t stream) {
    const float* ent_emb = (const float*)d_in[0];
    const float* rel_emb = (const float*)d_in[1];
    const int* e_src     = (const int*)d_in[2];
    const int* e_dst     = (const int*)d_in[3];
    const int* e_rel     = (const int*)d_in[4];
    const float* attn_e  = (const float*)d_in[5];
    const float* gate_e  = (const float*)d_in[6];
    const float* proxy_e = (const float*)d_in[7];
    const float* bias_e  = (const float*)d_in[8];
    const float* attn_r  = (const float*)d_in[9];
    const float* gate_r  = (const float*)d_in[10];
    const float* proxy_r = (const float*)d_in[11];
    const float* bias_r  = (const float*)d_in[12];
    float* out = (float*)d_out;
    (void)d_ws; (void)ws_size; (void)in_sizes; (void)n_in; (void)out_size;

    k_zero<<<(NN + 255) / 256, 256, 0, stream>>>();
    k_prep_rel<<<NR / 4, 256, 0, stream>>>(rel_emb, attn_e, attn_r);
    k_prep_proxy<<<32, 256, 0, stream>>>(proxy_e, proxy_r);
    k_prep_wt<<<(2 * FDIM * FDIM + 255) / 256, 256, 0, stream>>>(gate_e, gate_r);
    k_count<<<(NE + 255) / 256, 256, 0, stream>>>(e_dst);
    k_scan<<<1, 1024, 0, stream>>>();
    k_fill<<<(NE + 255) / 256, 256, 0, stream>>>(e_src, e_dst, e_rel);
    k_init<<<NN / 4, 256, 0, stream>>>(ent_emb, rel_emb, out);
    k_layer<<<dim3(NN / 4, 2), 256, 0, stream>>>(out, 0);
    k_layer<<<dim3(NN / 4, 2), 256, 0, stream>>>(out, 1);
    k_pg<<<dim3((NN + NPB - 1) / NPB, 2), 256, 0, stream>>>(out, bias_e, bias_r);
}

// Round 3
// 1228.554 us; speedup vs baseline: 1.3856x; 1.0995x over previous
//
#include <hip/hip_runtime.h>
#include <math.h>

// ---------------------------------------------------------------------------
// overAll_37606733644133 : relational GNN (2-layer Householder-reflection
// message passing with edge softmax) + proxy attention + gated mixing.
//
// Round-3 changes:
//  - k_pg: 512 threads / 8 waves per block (same NPB=32, LDS 58.9KB):
//    2 blocks/CU -> 16 waves/CU (4/SIMD) for latency hiding. Per-wave work
//    halved: wave w -> m-tile (w>>2), p-tile / f-quarter (w&3).
//  - k_layer: seg_max pass DELETED (softmax is shift-invariant; atab ~
//    N(0,0.01) so exp() is tame); per-(layer,rel) exp precomputed in
//    k_prep_rel (g_ew). Both duals fused into one pass (rn row shared,
//    2 interleaved shuffle chains), 2-edge unroll -> 4 concurrent chains.
//  - k_scan: hierarchical 3-kernel scan (49 parallel blocks) instead of
//    one block serially walking 49 chunks.
// ---------------------------------------------------------------------------

#define NN    50000
#define NE    800000
#define NR    2000
#define FF    128
#define FDIM  384
#define OD    768     // output row stride (2 duals x 384)
#define PP    64
#define NEPS  1e-12f
#define NPB   32      // nodes per k_pg block
#define FSTR  388     // LDS row stride (u32) for o/pf tile: 388%32=4 -> 2-way (free)
#define ASTR  68      // LDS row stride (u32) for att tile:  68%32=4 -> 2-way (free)
#define NBLK  49      // scan blocks: ceil(50000/1024)

typedef unsigned int u32;
typedef unsigned short u16;
typedef __attribute__((ext_vector_type(8))) short bf16x8;   // 8 bf16 (4 VGPRs)
typedef __attribute__((ext_vector_type(4))) float f32x4;

// ---- static device scratch ------------------------------------------------
__device__ int   g_rowptr[NN + 1];
__device__ int   g_cnt[NN];
__device__ int   g_bsum[64];
__device__ u32   g_csr[NE];               // (src<<16) | rel
__device__ float g_relnorm[NR * FF];
__device__ float2 g_ew[2 * NR];           // [layer][r] = (exp(atab_ent), exp(atab_rel))
// split-bf16 B-operands, all n-major / k-contiguous:
__device__ __attribute__((aligned(16))) u16 g_wt_hi[2 * FDIM * FDIM];  // [d][f][k] = W_d[k][f]
__device__ __attribute__((aligned(16))) u16 g_wt_lo[2 * FDIM * FDIM];
__device__ __attribute__((aligned(16))) u16 g_pxn_hi[2 * PP * FDIM];   // [d][p][k] = l2n(proxy_d[p])[k]
__device__ __attribute__((aligned(16))) u16 g_pxn_lo[2 * PP * FDIM];
__device__ __attribute__((aligned(16))) u16 g_pxT_hi[2 * FDIM * PP];   // [d][f][p] = proxy_d[p][f]
__device__ __attribute__((aligned(16))) u16 g_pxT_lo[2 * FDIM * PP];

__device__ __forceinline__ float wsum64(float v) {
#pragma unroll
    for (int m = 32; m > 0; m >>= 1) v += __shfl_xor(v, m, 64);
    return v;
}
__device__ __forceinline__ float wmax64(float v) {
#pragma unroll
    for (int m = 32; m > 0; m >>= 1) v = fmaxf(v, __shfl_xor(v, m, 64));
    return v;
}
// interleaved reductions: N independent 6-step chains pipeline in the DS unit
__device__ __forceinline__ void wsum64x2(float& a, float& b) {
#pragma unroll
    for (int m = 32; m > 0; m >>= 1) {
        float ta = __shfl_xor(a, m, 64);
        float tb = __shfl_xor(b, m, 64);
        a += ta; b += tb;
    }
}
__device__ __forceinline__ void wsum64x4(float& a, float& b, float& c, float& d) {
#pragma unroll
    for (int m = 32; m > 0; m >>= 1) {
        float ta = __shfl_xor(a, m, 64);
        float tb = __shfl_xor(b, m, 64);
        float tc = __shfl_xor(c, m, 64);
        float td = __shfl_xor(d, m, 64);
        a += ta; b += tb; c += tc; d += td;
    }
}

// fp32 -> (bf16_hi << 16) | bf16_lo, both RNE; hi+lo reconstructs to ~2^-16 rel
__device__ __forceinline__ u32 pack_bf(float f) {
    u32 x = __float_as_uint(f);
    u32 hr = (x + 0x7FFFu + ((x >> 16) & 1u)) & 0xFFFF0000u;
    float res = f - __uint_as_float(hr);
    u32 y = __float_as_uint(res);
    u32 lr = (y + 0x7FFFu + ((y >> 16) & 1u)) >> 16;
    return hr | lr;
}
__device__ __forceinline__ float unpack_bf(u32 pk) {
    return __uint_as_float(pk & 0xFFFF0000u) + __uint_as_float(pk << 16);
}

// read 8 packed elems (32B, 2x ds_read_b128) -> hi / lo bf16x8 fragments
__device__ __forceinline__ void load_afrag(const u32* p, bf16x8& ah, bf16x8& al) {
    u32 q[8];
    *reinterpret_cast<float4*>(q)     = *reinterpret_cast<const float4*>(p);
    *reinterpret_cast<float4*>(q + 4) = *reinterpret_cast<const float4*>(p + 4);
    union { u32 u[4]; bf16x8 v; } H, L;
#pragma unroll
    for (int j = 0; j < 4; j++) {
        H.u[j] = __builtin_amdgcn_perm(q[2 * j + 1], q[2 * j], 0x07060302u);
        L.u[j] = __builtin_amdgcn_perm(q[2 * j + 1], q[2 * j], 0x05040100u);
    }
    ah = H.v; al = L.v;
}

__global__ __launch_bounds__(256) void k_zero() {
    int i = blockIdx.x * 256 + threadIdx.x;
    if (i < NN) g_cnt[i] = 0;
}

// --- relnorm[r] = l2norm(rel_emb[r]); g_ew[l][r] = exp(relnorm.attn) both duals ---
__global__ __launch_bounds__(256) void k_prep_rel(
    const float* __restrict__ rel_emb, const float* __restrict__ attn_e,
    const float* __restrict__ attn_r) {
    int wave = threadIdx.x >> 6, lane = threadIdx.x & 63;
    int r = blockIdx.x * 4 + wave;
    if (r >= NR) return;
    float2 v = *(const float2*)(rel_emb + r * FF + 2 * lane);
    float ss = wsum64(v.x * v.x + v.y * v.y);
    float inv = 1.f / fmaxf(sqrtf(ss), NEPS);
    float rn0 = v.x * inv, rn1 = v.y * inv;
    *(float2*)(g_relnorm + r * FF + 2 * lane) = make_float2(rn0, rn1);
#pragma unroll
    for (int t = 0; t < 4; t++) {   // t = dual*2 + layer
        const float* av = ((t < 2) ? attn_e : attn_r) + (t & 1) * FF + 2 * lane;
        float d = wsum64(rn0 * av[0] + rn1 * av[1]);
        if (lane == 0) ((float*)&g_ew[(t & 1) * NR + r])[t >> 1] = expf(d);
    }
}

// --- split-bf16 proxy tables: l2n rows ([d][p][k]) and raw transpose ([d][f][p]) ---
__global__ __launch_bounds__(256) void k_prep_proxy(
    const float* __restrict__ proxy_e, const float* __restrict__ proxy_r) {
    int wave = threadIdx.x >> 6, lane = threadIdx.x & 63;
    int row = blockIdx.x * 4 + wave;  // 0..127
    if (row >= 2 * PP) return;
    int d = row >> 6, p = row & 63;
    const float* pr = ((d == 0) ? proxy_e : proxy_r) + p * FDIM;
    float v[6];
    float ss = 0.f;
#pragma unroll
    for (int j = 0; j < 6; j++) {
        v[j] = pr[lane + 64 * j];
        ss += v[j] * v[j];
    }
    ss = wsum64(ss);
    float inv = 1.f / fmaxf(sqrtf(ss), NEPS);
#pragma unroll
    for (int j = 0; j < 6; j++) {
        int k = lane + 64 * j;
        u32 pn = pack_bf(v[j] * inv);
        g_pxn_hi[(d * PP + p) * FDIM + k] = (u16)(pn >> 16);
        g_pxn_lo[(d * PP + p) * FDIM + k] = (u16)(pn & 0xFFFFu);
        u32 pt = pack_bf(v[j]);
        g_pxT_hi[(d * FDIM + k) * PP + p] = (u16)(pt >> 16);
        g_pxT_lo[(d * FDIM + k) * PP + p] = (u16)(pt & 0xFFFFu);
    }
}

// --- split-bf16 gate weights, transposed: wt[d][f][k] = W_d[k][f] ---
__global__ __launch_bounds__(256) void k_prep_wt(
    const float* __restrict__ gate_e, const float* __restrict__ gate_r) {
    int idx = blockIdx.x * 256 + threadIdx.x;
    if (idx >= 2 * FDIM * FDIM) return;
    int d = idx / (FDIM * FDIM);
    int rem = idx - d * (FDIM * FDIM);
    int k = rem / FDIM;
    int f = rem - k * FDIM;          // consecutive lanes -> consecutive f: coalesced read
    float wv = (d ? gate_r : gate_e)[k * FDIM + f];
    u32 pk = pack_bf(wv);
    g_wt_hi[(d * FDIM + f) * FDIM + k] = (u16)(pk >> 16);
    g_wt_lo[(d * FDIM + f) * FDIM + k] = (u16)(pk & 0xFFFFu);
}

__global__ __launch_bounds__(256) void k_count(const int* __restrict__ dst) {
    int e = blockIdx.x * 256 + threadIdx.x;
    if (e < NE) atomicAdd(&g_cnt[dst[e]], 1);
}

// --- hierarchical exclusive scan: per-block scan -> block-sum scan -> add ---
__global__ __launch_bounds__(1024) void k_scan1() {
    __shared__ int s[1024];
    int b = blockIdx.x, tid = threadIdx.x;
    int i = b * 1024 + tid;
    int v = (i < NN) ? g_cnt[i] : 0;
    s[tid] = v;
    __syncthreads();
    for (int off = 1; off < 1024; off <<= 1) {
        int t = (tid >= off) ? s[tid - off] : 0;
        __syncthreads();
        s[tid] += t;
        __syncthreads();
    }
    if (i < NN) {
        g_rowptr[i] = s[tid] - v;   // exclusive within block
        g_cnt[i] = 0;
    }
    if (tid == 1023) g_bsum[b] = s[1023];
}
__global__ __launch_bounds__(64) void k_scan2() {
    int lane = threadIdx.x;
    int v = (lane < NBLK) ? g_bsum[lane] : 0;
#pragma unroll
    for (int off = 1; off < 64; off <<= 1) {
        int t = __shfl_up(v, off, 64);
        if (lane >= off) v += t;
    }
    if (lane < NBLK) g_bsum[lane] = v;  // inclusive block-sum scan
    if (lane == 0) g_rowptr[NN] = NE;
}
__global__ __launch_bounds__(1024) void k_scan3() {
    int b = blockIdx.x;
    if (b == 0) return;
    int i = b * 1024 + threadIdx.x;
    if (i < NN) g_rowptr[i] += g_bsum[b - 1];
}

__global__ __launch_bounds__(256) void k_fill(
    const int* __restrict__ src, const int* __restrict__ dst,
    const int* __restrict__ rel) {
    int e = blockIdx.x * 256 + threadIdx.x;
    if (e >= NE) return;
    int d = dst[e];
    int pos = atomicAdd(&g_cnt[d], 1);
    g_csr[g_rowptr[d] + pos] = ((u32)src[e] << 16) | (u32)rel[e];
}

// --- initial features: tanh(mean over incoming edges), both duals ---
__global__ __launch_bounds__(256) void k_init(
    const float* __restrict__ ent_emb, const float* __restrict__ rel_emb,
    float* __restrict__ out) {
    int wave = threadIdx.x >> 6, lane = threadIdx.x & 63;
    int n = blockIdx.x * 4 + wave;
    if (n >= NN) return;
    int s0 = g_rowptr[n], s1 = g_rowptr[n + 1];
    float ae0 = 0, ae1 = 0, ar0 = 0, ar1 = 0;
    for (int idx = s0; idx < s1; idx++) {
        u32 pk = g_csr[idx];
        int s = __builtin_amdgcn_readfirstlane((int)(pk >> 16));
        int r = __builtin_amdgcn_readfirstlane((int)(pk & 0xFFFFu));
        float2 ue = *(const float2*)(ent_emb + s * FF + 2 * lane);
        float2 ur = *(const float2*)(rel_emb + r * FF + 2 * lane);
        ae0 += ue.x; ae1 += ue.y;
        ar0 += ur.x; ar1 += ur.y;
    }
    float invd = 1.f / (float)max(s1 - s0, 1);
    *(float2*)(out + n * OD + 2 * lane) =
        make_float2(tanhf(ae0 * invd), tanhf(ae1 * invd));
    *(float2*)(out + n * OD + FDIM + 2 * lane) =
        make_float2(tanhf(ar0 * invd), tanhf(ar1 * invd));
}

// --- one message-passing layer, BOTH duals fused: wave per node ---
// softmax needs no max-subtraction (shift-invariant; atab ~ N(0,0.01)).
// exp weights pre-tabulated in g_ew[layer][r] = (w_ent, w_rel).
__global__ __launch_bounds__(256) void k_layer(float* buf, int layer) {
    int wave = threadIdx.x >> 6, lane = threadIdx.x & 63;
    int n = blockIdx.x * 4 + wave;
    if (n >= NN) return;
    int bi_e = layer * FF;           // ent input cols
    int bi_r = FDIM + layer * FF;    // rel input cols
    const float2* ew = g_ew + layer * NR;
    int s0 = g_rowptr[n], s1 = g_rowptr[n + 1];
    float* oe = buf + n * OD + bi_e + FF + 2 * lane;
    float* orr = buf + n * OD + bi_r + FF + 2 * lane;
    if (s1 == s0) {
        *(float2*)oe = make_float2(0.f, 0.f);
        *(float2*)orr = make_float2(0.f, 0.f);
        return;
    }
    float ae0 = 0, ae1 = 0, wse = 0;
    float ar0 = 0, ar1 = 0, wsr = 0;
    int idx = s0;
    for (; idx + 2 <= s1; idx += 2) {   // 2-edge unroll: 4 concurrent shuffle chains
        u32 pk0 = g_csr[idx], pk1 = g_csr[idx + 1];
        int sa = __builtin_amdgcn_readfirstlane((int)(pk0 >> 16));
        int ra = __builtin_amdgcn_readfirstlane((int)(pk0 & 0xFFFFu));
        int sb = __builtin_amdgcn_readfirstlane((int)(pk1 >> 16));
        int rb = __builtin_amdgcn_readfirstlane((int)(pk1 & 0xFFFFu));
        float2 hea = *(const float2*)(buf + sa * OD + bi_e + 2 * lane);
        float2 hra = *(const float2*)(buf + sa * OD + bi_r + 2 * lane);
        float2 rna = *(const float2*)(g_relnorm + ra * FF + 2 * lane);
        float2 heb = *(const float2*)(buf + sb * OD + bi_e + 2 * lane);
        float2 hrb = *(const float2*)(buf + sb * OD + bi_r + 2 * lane);
        float2 rnb = *(const float2*)(g_relnorm + rb * FF + 2 * lane);
        float dea = hea.x * rna.x + hea.y * rna.y;
        float dra = hra.x * rna.x + hra.y * rna.y;
        float deb = heb.x * rnb.x + heb.y * rnb.y;
        float drb = hrb.x * rnb.x + hrb.y * rnb.y;
        wsum64x4(dea, dra, deb, drb);
        float2 wa = ew[ra], wb = ew[rb];
        wse += wa.x + wb.x;
        wsr += wa.y + wb.y;
        ae0 += wa.x * (hea.x - 2.f * dea * rna.x) + wb.x * (heb.x - 2.f * deb * rnb.x);
        ae1 += wa.x * (hea.y - 2.f * dea * rna.y) + wb.x * (heb.y - 2.f * deb * rnb.y);
        ar0 += wa.y * (hra.x - 2.f * dra * rna.x) + wb.y * (hrb.x - 2.f * drb * rnb.x);
        ar1 += wa.y * (hra.y - 2.f * dra * rna.y) + wb.y * (hrb.y - 2.f * drb * rnb.y);
    }
    if (idx < s1) {                      // tail edge
        u32 pk = g_csr[idx];
        int s = __builtin_amdgcn_readfirstlane((int)(pk >> 16));
        int r = __builtin_amdgcn_readfirstlane((int)(pk & 0xFFFFu));
        float2 he = *(const float2*)(buf + s * OD + bi_e + 2 * lane);
        float2 hr = *(const float2*)(buf + s * OD + bi_r + 2 * lane);
        float2 rn = *(const float2*)(g_relnorm + r * FF + 2 * lane);
        float de = he.x * rn.x + he.y * rn.y;
        float dr = hr.x * rn.x + hr.y * rn.y;
        wsum64x2(de, dr);
        float2 w2 = ew[r];
        wse += w2.x; wsr += w2.y;
        ae0 += w2.x * (he.x - 2.f * de * rn.x);
        ae1 += w2.x * (he.y - 2.f * de * rn.y);
        ar0 += w2.y * (hr.x - 2.f * dr * rn.x);
        ar1 += w2.y * (hr.y - 2.f * dr * rn.y);
    }
    float ive = 1.f / wse, ivr = 1.f / wsr;
    *(float2*)oe = make_float2(tanhf(ae0 * ive), tanhf(ae1 * ive));
    *(float2*)orr = make_float2(tanhf(ar0 * ivr), tanhf(ar1 * ivr));
}

// --- fused proxy attention + gate, MFMA v4: 32 nodes/block, 8 waves, y = dual ---
// wave w: m-tile mw = w>>2 (16 rows), quarter q = w&3 (p-tile / 96-col f-slab).
__global__ __launch_bounds__(512, 4) void k_pg(
    float* out, const float* __restrict__ bias_e,
    const float* __restrict__ bias_r) {
    __shared__ __attribute__((aligned(16))) u32 o_pk[NPB * FSTR];   // 49.7 KB
    __shared__ __attribute__((aligned(16))) u32 att_pk[NPB * ASTR]; // 8.7 KB
    __shared__ float invn_s[NPB];
    int tid = threadIdx.x;
    int lane = tid & 63, w = tid >> 6;    // 8 waves
    int c = lane & 15, kg = lane >> 4;    // MFMA fragment coords
    int mw = w >> 2, q = w & 3;
    int n0 = blockIdx.x * NPB, dual = blockIdx.y;
    int dual_off = dual * FDIM;
    const float* bias = dual ? bias_r : bias_e;
    const u16* wt_h = g_wt_hi + dual * (FDIM * FDIM);
    const u16* wt_l = g_wt_lo + dual * (FDIM * FDIM);
    const u16* pn_h = g_pxn_hi + dual * (PP * FDIM);
    const u16* pn_l = g_pxn_lo + dual * (PP * FDIM);
    const u16* pt_h = g_pxT_hi + dual * (FDIM * PP);
    const u16* pt_l = g_pxT_lo + dual * (FDIM * PP);

    // ---- phase 1: stage + sumsq + pack (wave w: rows w+8j) ----
#pragma unroll
    for (int j = 0; j < 4; j++) {
        int n = w + 8 * j;
        int gn = n0 + n;
        float2 v[3];
        if (gn < NN) {
            const float* rp = out + (size_t)gn * OD + dual_off;
#pragma unroll
            for (int p = 0; p < 3; p++) v[p] = *(const float2*)(rp + 2 * (lane + 64 * p));
        } else {
            v[0] = v[1] = v[2] = make_float2(0.f, 0.f);
        }
        float ss = 0.f;
#pragma unroll
        for (int p = 0; p < 3; p++) ss += v[p].x * v[p].x + v[p].y * v[p].y;
        ss = wsum64(ss);
        if (lane == 0) invn_s[n] = 1.f / fmaxf(sqrtf(ss), NEPS);
#pragma unroll
        for (int p = 0; p < 3; p++) {
            uint2 pr;
            pr.x = pack_bf(v[p].x);
            pr.y = pack_bf(v[p].y);
            *(uint2*)(o_pk + n * FSTR + 2 * (lane + 64 * p)) = pr;
        }
    }
    __syncthreads();

    // ---- phase 2: logits tile (m=mw, p-tile q) = (o @ l2n(proxy)^T)*invn ----
    {
        f32x4 lacc = {0.f, 0.f, 0.f, 0.f};
        const u16* bh_p = pn_h + (16 * q + c) * FDIM;
        const u16* bl_p = pn_l + (16 * q + c) * FDIM;
        const u32* ap = o_pk + (16 * mw + c) * FSTR;
        for (int ks = 0; ks < 12; ks++) {
            int kb = 32 * ks + 8 * kg;
            bf16x8 ah, al;
            load_afrag(ap + kb, ah, al);
            bf16x8 bh = *(const bf16x8*)(bh_p + kb);
            bf16x8 bl = *(const bf16x8*)(bl_p + kb);
            lacc = __builtin_amdgcn_mfma_f32_16x16x32_bf16(ah, bh, lacc, 0, 0, 0);
            lacc = __builtin_amdgcn_mfma_f32_16x16x32_bf16(al, bh, lacc, 0, 0, 0);
            lacc = __builtin_amdgcn_mfma_f32_16x16x32_bf16(ah, bl, lacc, 0, 0, 0);
        }
#pragma unroll
        for (int i = 0; i < 4; i++) {
            int n = 16 * mw + 4 * kg + i;
            att_pk[n * ASTR + 16 * q + c] = __float_as_uint(lacc[i] * invn_s[n]);
        }
    }
    __syncthreads();

    // ---- phase 3: softmax over P=64 + pack (wave w: rows w+8j) ----
#pragma unroll
    for (int j = 0; j < 4; j++) {
        int n = w + 8 * j;
        float l = __uint_as_float(att_pk[n * ASTR + lane]);
        float mx = wmax64(l);
        float e = expf(l - mx);
        float s = wsum64(e);
        att_pk[n * ASTR + lane] = pack_bf(e / s);
    }
    __syncthreads();

    // ---- phase 4: pf = o - att @ proxy (K=64); repack pf over o in place ----
    f32x4 pacc[6];
#pragma unroll
    for (int t = 0; t < 6; t++) pacc[t] = (f32x4){0.f, 0.f, 0.f, 0.f};
    {
        bf16x8 aah[2], aal[2];
        load_afrag(att_pk + (16 * mw + c) * ASTR + 8 * kg, aah[0], aal[0]);
        load_afrag(att_pk + (16 * mw + c) * ASTR + 32 + 8 * kg, aah[1], aal[1]);
#pragma unroll
        for (int t = 0; t < 6; t++) {
            int f = 96 * q + 16 * t + c;
            const u16* bh0 = pt_h + f * PP;
            const u16* bl0 = pt_l + f * PP;
            bf16x8 b0h = *(const bf16x8*)(bh0 + 8 * kg);
            bf16x8 b0l = *(const bf16x8*)(bl0 + 8 * kg);
            bf16x8 b1h = *(const bf16x8*)(bh0 + 32 + 8 * kg);
            bf16x8 b1l = *(const bf16x8*)(bl0 + 32 + 8 * kg);
            pacc[t] = __builtin_amdgcn_mfma_f32_16x16x32_bf16(aah[0], b0h, pacc[t], 0, 0, 0);
            pacc[t] = __builtin_amdgcn_mfma_f32_16x16x32_bf16(aal[0], b0h, pacc[t], 0, 0, 0);
            pacc[t] = __builtin_amdgcn_mfma_f32_16x16x32_bf16(aah[0], b0l, pacc[t], 0, 0, 0);
            pacc[t] = __builtin_amdgcn_mfma_f32_16x16x32_bf16(aah[1], b1h, pacc[t], 0, 0, 0);
            pacc[t] = __builtin_amdgcn_mfma_f32_16x16x32_bf16(aal[1], b1h, pacc[t], 0, 0, 0);
            pacc[t] = __builtin_amdgcn_mfma_f32_16x16x32_bf16(aah[1], b1l, pacc[t], 0, 0, 0);
        }
#pragma unroll
        for (int t = 0; t < 6; t++) {
            int f = 96 * q + 16 * t + c;
#pragma unroll
            for (int i = 0; i < 4; i++) {
                int n = 16 * mw + 4 * kg + i;
                u32 pk = o_pk[n * FSTR + f];
                o_pk[n * FSTR + f] = pack_bf(unpack_bf(pk) - pacc[t][i]);
            }
        }
    }
    __syncthreads();

    // ---- phase 5: gate GEMM lin = pf @ W (wave: m=mw, f-slab 96q..96q+95) ----
    f32x4 gacc[6];
#pragma unroll
    for (int t = 0; t < 6; t++) gacc[t] = (f32x4){0.f, 0.f, 0.f, 0.f};
    {
        const u16* wtw_h = wt_h + (96 * q + c) * FDIM;
        const u16* wtw_l = wt_l + (96 * q + c) * FDIM;
        const u32* ap = o_pk + (16 * mw + c) * FSTR;
        for (int ks = 0; ks < 12; ks++) {
            int kb = 32 * ks + 8 * kg;
            bf16x8 bh[6];
#pragma unroll
            for (int t = 0; t < 6; t++)
                bh[t] = *(const bf16x8*)(wtw_h + t * 16 * FDIM + kb);
            bf16x8 ah, al;
            load_afrag(ap + kb, ah, al);
#pragma unroll
            for (int t = 0; t < 6; t++) {
                bf16x8 bl = *(const bf16x8*)(wtw_l + t * 16 * FDIM + kb);
                gacc[t] = __builtin_amdgcn_mfma_f32_16x16x32_bf16(ah, bh[t], gacc[t], 0, 0, 0);
                gacc[t] = __builtin_amdgcn_mfma_f32_16x16x32_bf16(al, bh[t], gacc[t], 0, 0, 0);
                gacc[t] = __builtin_amdgcn_mfma_f32_16x16x32_bf16(ah, bl, gacc[t], 0, 0, 0);
            }
        }
    }

    // ---- epilogue: gt = sigmoid(lin+bias); o = pf + pacc; out = gt*o+(1-gt)*pf ----
#pragma unroll
    for (int t = 0; t < 6; t++) {
        int fcol = 96 * q + 16 * t + c;
        float b = bias[fcol];
#pragma unroll
        for (int i = 0; i < 4; i++) {
            int n = 16 * mw + 4 * kg + i;
            int gn = n0 + n;
            if (gn < NN) {
                float lin = gacc[t][i] + b;
                float gt = 1.f / (1.f + expf(-lin));
                float pv = unpack_bf(o_pk[n * FSTR + fcol]);
                float ov = pv + pacc[t][i];
                out[(size_t)gn * OD + dual_off + fcol] = gt * ov + (1.f - gt) * pv;
            }
        }
    }
}

extern "C" void kernel_launch(void* const* d_in, const int* in_sizes, int n_in,
                              void* d_out, int out_size, void* d_ws, size_t ws_size,
                              hipStream_t stream) {
    const float* ent_emb = (const float*)d_in[0];
    const float* rel_emb = (const float*)d_in[1];
    const int* e_src     = (const int*)d_in[2];
    const int* e_dst     = (const int*)d_in[3];
    const int* e_rel     = (const int*)d_in[4];
    const float* attn_e  = (const float*)d_in[5];
    const float* gate_e  = (const float*)d_in[6];
    const float* proxy_e = (const float*)d_in[7];
    const float* bias_e  = (const float*)d_in[8];
    const float* attn_r  = (const float*)d_in[9];
    const float* gate_r  = (const float*)d_in[10];
    const float* proxy_r = (const float*)d_in[11];
    const float* bias_r  = (const float*)d_in[12];
    float* out = (float*)d_out;
    (void)d_ws; (void)ws_size; (void)in_sizes; (void)n_in; (void)out_size;

    k_zero<<<(NN + 255) / 256, 256, 0, stream>>>();
    k_prep_rel<<<NR / 4, 256, 0, stream>>>(rel_emb, attn_e, attn_r);
    k_prep_proxy<<<32, 256, 0, stream>>>(proxy_e, proxy_r);
    k_prep_wt<<<(2 * FDIM * FDIM + 255) / 256, 256, 0, stream>>>(gate_e, gate_r);
    k_count<<<(NE + 255) / 256, 256, 0, stream>>>(e_dst);
    k_scan1<<<NBLK, 1024, 0, stream>>>();
    k_scan2<<<1, 64, 0, stream>>>();
    k_scan3<<<NBLK, 1024, 0, stream>>>();
    k_fill<<<(NE + 255) / 256, 256, 0, stream>>>(e_src, e_dst, e_rel);
    k_init<<<NN / 4, 256, 0, stream>>>(ent_emb, rel_emb, out);
    k_layer<<<NN / 4, 256, 0, stream>>>(out, 0);
    k_layer<<<NN / 4, 256, 0, stream>>>(out, 1);
    k_pg<<<dim3((NN + NPB - 1) / NPB, 2), 512, 0, stream>>>(out, bias_e, bias_r);
}

// Round 4
// 1017.212 us; speedup vs baseline: 1.6735x; 1.2078x over previous
//
#include <hip/hip_runtime.h>
#include <math.h>

// ---------------------------------------------------------------------------
// overAll_37606733644133 : relational GNN (2-layer Householder-reflection
// message passing with edge softmax) + proxy attention + gated mixing.
//
// Round-4:
//  - k_pg reverted to the round-2 winner (256 thr, 2 m-tiles x 6 t per wave,
//    all 12 B-frags hoisted per K-step, unroll 2): thin-wave round-3 variant
//    regressed (B reuse halved, bl loads serialized).
//  - k_layer/k_init: 16-lane-group edge parallelism — 4 edges per wave,
//    8 features per lane, dot reduced by 4-step intra-group shfl_xor
//    (2 shuffle instrs/edge vs 12), cross-group reduce once per node.
//  - keeps: fused-dual k_layer, g_ew exp table (no seg_max), hierarchical scan.
// ---------------------------------------------------------------------------

#define NN    50000
#define NE    800000
#define NR    2000
#define FF    128
#define FDIM  384
#define OD    768     // output row stride (2 duals x 384)
#define PP    64
#define NEPS  1e-12f
#define NPB   32      // nodes per k_pg block
#define FSTR  388     // LDS row stride (u32) for o/pf tile: 388%32=4 -> 2-way (free)
#define ASTR  68      // LDS row stride (u32) for att tile:  68%32=4 -> 2-way (free)
#define NBLK  49      // scan blocks: ceil(50000/1024)

typedef unsigned int u32;
typedef unsigned short u16;
typedef __attribute__((ext_vector_type(8))) short bf16x8;   // 8 bf16 (4 VGPRs)
typedef __attribute__((ext_vector_type(4))) float f32x4;

// ---- static device scratch ------------------------------------------------
__device__ int   g_rowptr[NN + 1];
__device__ int   g_cnt[NN];
__device__ int   g_bsum[64];
__device__ u32   g_csr[NE];               // (src<<16) | rel
__device__ float g_relnorm[NR * FF];
__device__ float2 g_ew[2 * NR];           // [layer][r] = (exp(atab_ent), exp(atab_rel))
// split-bf16 B-operands, all n-major / k-contiguous:
__device__ __attribute__((aligned(16))) u16 g_wt_hi[2 * FDIM * FDIM];  // [d][f][k] = W_d[k][f]
__device__ __attribute__((aligned(16))) u16 g_wt_lo[2 * FDIM * FDIM];
__device__ __attribute__((aligned(16))) u16 g_pxn_hi[2 * PP * FDIM];   // [d][p][k] = l2n(proxy_d[p])[k]
__device__ __attribute__((aligned(16))) u16 g_pxn_lo[2 * PP * FDIM];
__device__ __attribute__((aligned(16))) u16 g_pxT_hi[2 * FDIM * PP];   // [d][f][p] = proxy_d[p][f]
__device__ __attribute__((aligned(16))) u16 g_pxT_lo[2 * FDIM * PP];

__device__ __forceinline__ float wsum64(float v) {
#pragma unroll
    for (int m = 32; m > 0; m >>= 1) v += __shfl_xor(v, m, 64);
    return v;
}
__device__ __forceinline__ float wmax64(float v) {
#pragma unroll
    for (int m = 32; m > 0; m >>= 1) v = fmaxf(v, __shfl_xor(v, m, 64));
    return v;
}
// 16-lane-group sum (masks 1,2,4,8), two values interleaved
__device__ __forceinline__ void red16x2(float& a, float& b) {
#pragma unroll
    for (int m = 1; m < 16; m <<= 1) {
        float ta = __shfl_xor(a, m, 64);
        float tb = __shfl_xor(b, m, 64);
        a += ta; b += tb;
    }
}
// cross-group (4x16) reduction over masks 16,32
__device__ __forceinline__ void xgr4(float4& v) {
#pragma unroll
    for (int mk = 16; mk < 64; mk <<= 1) {
        v.x += __shfl_xor(v.x, mk, 64);
        v.y += __shfl_xor(v.y, mk, 64);
        v.z += __shfl_xor(v.z, mk, 64);
        v.w += __shfl_xor(v.w, mk, 64);
    }
}
__device__ __forceinline__ void xgr1(float& v) {
#pragma unroll
    for (int mk = 16; mk < 64; mk <<= 1) v += __shfl_xor(v, mk, 64);
}

// fp32 -> (bf16_hi << 16) | bf16_lo, both RNE; hi+lo reconstructs to ~2^-16 rel
__device__ __forceinline__ u32 pack_bf(float f) {
    u32 x = __float_as_uint(f);
    u32 hr = (x + 0x7FFFu + ((x >> 16) & 1u)) & 0xFFFF0000u;
    float res = f - __uint_as_float(hr);
    u32 y = __float_as_uint(res);
    u32 lr = (y + 0x7FFFu + ((y >> 16) & 1u)) >> 16;
    return hr | lr;
}
__device__ __forceinline__ float unpack_bf(u32 pk) {
    return __uint_as_float(pk & 0xFFFF0000u) + __uint_as_float(pk << 16);
}

// read 8 packed elems (32B, 2x ds_read_b128) -> hi / lo bf16x8 fragments
__device__ __forceinline__ void load_afrag(const u32* p, bf16x8& ah, bf16x8& al) {
    u32 q[8];
    *reinterpret_cast<float4*>(q)     = *reinterpret_cast<const float4*>(p);
    *reinterpret_cast<float4*>(q + 4) = *reinterpret_cast<const float4*>(p + 4);
    union { u32 u[4]; bf16x8 v; } H, L;
#pragma unroll
    for (int j = 0; j < 4; j++) {
        H.u[j] = __builtin_amdgcn_perm(q[2 * j + 1], q[2 * j], 0x07060302u);
        L.u[j] = __builtin_amdgcn_perm(q[2 * j + 1], q[2 * j], 0x05040100u);
    }
    ah = H.v; al = L.v;
}

__global__ __launch_bounds__(256) void k_zero() {
    int i = blockIdx.x * 256 + threadIdx.x;
    if (i < NN) g_cnt[i] = 0;
}

// --- relnorm[r] = l2norm(rel_emb[r]); g_ew[l][r] = exp(relnorm.attn) both duals ---
__global__ __launch_bounds__(256) void k_prep_rel(
    const float* __restrict__ rel_emb, const float* __restrict__ attn_e,
    const float* __restrict__ attn_r) {
    int wave = threadIdx.x >> 6, lane = threadIdx.x & 63;
    int r = blockIdx.x * 4 + wave;
    if (r >= NR) return;
    float2 v = *(const float2*)(rel_emb + r * FF + 2 * lane);
    float ss = wsum64(v.x * v.x + v.y * v.y);
    float inv = 1.f / fmaxf(sqrtf(ss), NEPS);
    float rn0 = v.x * inv, rn1 = v.y * inv;
    *(float2*)(g_relnorm + r * FF + 2 * lane) = make_float2(rn0, rn1);
#pragma unroll
    for (int t = 0; t < 4; t++) {   // t = dual*2 + layer
        const float* av = ((t < 2) ? attn_e : attn_r) + (t & 1) * FF + 2 * lane;
        float d = wsum64(rn0 * av[0] + rn1 * av[1]);
        if (lane == 0) ((float*)&g_ew[(t & 1) * NR + r])[t >> 1] = expf(d);
    }
}

// --- split-bf16 proxy tables: l2n rows ([d][p][k]) and raw transpose ([d][f][p]) ---
__global__ __launch_bounds__(256) void k_prep_proxy(
    const float* __restrict__ proxy_e, const float* __restrict__ proxy_r) {
    int wave = threadIdx.x >> 6, lane = threadIdx.x & 63;
    int row = blockIdx.x * 4 + wave;  // 0..127
    if (row >= 2 * PP) return;
    int d = row >> 6, p = row & 63;
    const float* pr = ((d == 0) ? proxy_e : proxy_r) + p * FDIM;
    float v[6];
    float ss = 0.f;
#pragma unroll
    for (int j = 0; j < 6; j++) {
        v[j] = pr[lane + 64 * j];
        ss += v[j] * v[j];
    }
    ss = wsum64(ss);
    float inv = 1.f / fmaxf(sqrtf(ss), NEPS);
#pragma unroll
    for (int j = 0; j < 6; j++) {
        int k = lane + 64 * j;
        u32 pn = pack_bf(v[j] * inv);
        g_pxn_hi[(d * PP + p) * FDIM + k] = (u16)(pn >> 16);
        g_pxn_lo[(d * PP + p) * FDIM + k] = (u16)(pn & 0xFFFFu);
        u32 pt = pack_bf(v[j]);
        g_pxT_hi[(d * FDIM + k) * PP + p] = (u16)(pt >> 16);
        g_pxT_lo[(d * FDIM + k) * PP + p] = (u16)(pt & 0xFFFFu);
    }
}

// --- split-bf16 gate weights, transposed: wt[d][f][k] = W_d[k][f] ---
__global__ __launch_bounds__(256) void k_prep_wt(
    const float* __restrict__ gate_e, const float* __restrict__ gate_r) {
    int idx = blockIdx.x * 256 + threadIdx.x;
    if (idx >= 2 * FDIM * FDIM) return;
    int d = idx / (FDIM * FDIM);
    int rem = idx - d * (FDIM * FDIM);
    int k = rem / FDIM;
    int f = rem - k * FDIM;          // consecutive lanes -> consecutive f: coalesced read
    float wv = (d ? gate_r : gate_e)[k * FDIM + f];
    u32 pk = pack_bf(wv);
    g_wt_hi[(d * FDIM + f) * FDIM + k] = (u16)(pk >> 16);
    g_wt_lo[(d * FDIM + f) * FDIM + k] = (u16)(pk & 0xFFFFu);
}

__global__ __launch_bounds__(256) void k_count(const int* __restrict__ dst) {
    int e = blockIdx.x * 256 + threadIdx.x;
    if (e < NE) atomicAdd(&g_cnt[dst[e]], 1);
}

// --- hierarchical exclusive scan: per-block scan -> block-sum scan -> add ---
__global__ __launch_bounds__(1024) void k_scan1() {
    __shared__ int s[1024];
    int b = blockIdx.x, tid = threadIdx.x;
    int i = b * 1024 + tid;
    int v = (i < NN) ? g_cnt[i] : 0;
    s[tid] = v;
    __syncthreads();
    for (int off = 1; off < 1024; off <<= 1) {
        int t = (tid >= off) ? s[tid - off] : 0;
        __syncthreads();
        s[tid] += t;
        __syncthreads();
    }
    if (i < NN) {
        g_rowptr[i] = s[tid] - v;   // exclusive within block
        g_cnt[i] = 0;
    }
    if (tid == 1023) g_bsum[b] = s[1023];
}
__global__ __launch_bounds__(64) void k_scan2() {
    int lane = threadIdx.x;
    int v = (lane < NBLK) ? g_bsum[lane] : 0;
#pragma unroll
    for (int off = 1; off < 64; off <<= 1) {
        int t = __shfl_up(v, off, 64);
        if (lane >= off) v += t;
    }
    if (lane < NBLK) g_bsum[lane] = v;  // inclusive block-sum scan
    if (lane == 0) g_rowptr[NN] = NE;
}
__global__ __launch_bounds__(1024) void k_scan3() {
    int b = blockIdx.x;
    if (b == 0) return;
    int i = b * 1024 + threadIdx.x;
    if (i < NN) g_rowptr[i] += g_bsum[b - 1];
}

__global__ __launch_bounds__(256) void k_fill(
    const int* __restrict__ src, const int* __restrict__ dst,
    const int* __restrict__ rel) {
    int e = blockIdx.x * 256 + threadIdx.x;
    if (e >= NE) return;
    int d = dst[e];
    int pos = atomicAdd(&g_cnt[d], 1);
    g_csr[g_rowptr[d] + pos] = ((u32)src[e] << 16) | (u32)rel[e];
}

// --- initial features: tanh(mean over incoming edges), both duals ---
// 4 edges/wave (16-lane groups), 8 features per lane.
__global__ __launch_bounds__(256) void k_init(
    const float* __restrict__ ent_emb, const float* __restrict__ rel_emb,
    float* __restrict__ out) {
    int wave = threadIdx.x >> 6, lane = threadIdx.x & 63;
    int n = blockIdx.x * 4 + wave;
    if (n >= NN) return;
    int g16 = lane >> 4, li = lane & 15;
    int s0 = g_rowptr[n], s1 = g_rowptr[n + 1];
    float4 aeA = {0,0,0,0}, aeB = {0,0,0,0}, arA = {0,0,0,0}, arB = {0,0,0,0};
    for (int idx = s0; idx < s1; idx += 4) {
        int e = idx + g16;
        if (e < s1) {
            u32 pk = g_csr[e];
            int s = (int)(pk >> 16), r = (int)(pk & 0xFFFFu);
            const float* up = ent_emb + (size_t)s * FF + 8 * li;
            const float* rp = rel_emb + (size_t)r * FF + 8 * li;
            float4 u0 = *(const float4*)up, u1 = *(const float4*)(up + 4);
            float4 r0 = *(const float4*)rp, r1 = *(const float4*)(rp + 4);
            aeA.x += u0.x; aeA.y += u0.y; aeA.z += u0.z; aeA.w += u0.w;
            aeB.x += u1.x; aeB.y += u1.y; aeB.z += u1.z; aeB.w += u1.w;
            arA.x += r0.x; arA.y += r0.y; arA.z += r0.z; arA.w += r0.w;
            arB.x += r1.x; arB.y += r1.y; arB.z += r1.z; arB.w += r1.w;
        }
    }
    xgr4(aeA); xgr4(aeB); xgr4(arA); xgr4(arB);
    float invd = 1.f / (float)max(s1 - s0, 1);
    if (g16 == 0) {
        float* oe = out + (size_t)n * OD + 8 * li;
        float* orp = out + (size_t)n * OD + FDIM + 8 * li;
        *(float4*)oe = make_float4(tanhf(aeA.x * invd), tanhf(aeA.y * invd),
                                   tanhf(aeA.z * invd), tanhf(aeA.w * invd));
        *(float4*)(oe + 4) = make_float4(tanhf(aeB.x * invd), tanhf(aeB.y * invd),
                                         tanhf(aeB.z * invd), tanhf(aeB.w * invd));
        *(float4*)orp = make_float4(tanhf(arA.x * invd), tanhf(arA.y * invd),
                                    tanhf(arA.z * invd), tanhf(arA.w * invd));
        *(float4*)(orp + 4) = make_float4(tanhf(arB.x * invd), tanhf(arB.y * invd),
                                          tanhf(arB.z * invd), tanhf(arB.w * invd));
    }
}

// --- one message-passing layer, BOTH duals fused, 4 edges/wave ---
// 16-lane group per edge, 8 features/lane; dot via 4-step intra-group
// shfl_xor; cross-group reduce once per node. exp weights in g_ew.
__global__ __launch_bounds__(256) void k_layer(float* buf, int layer) {
    int wave = threadIdx.x >> 6, lane = threadIdx.x & 63;
    int n = blockIdx.x * 4 + wave;
    if (n >= NN) return;
    int g16 = lane >> 4, li = lane & 15;
    int bi_e = layer * FF, bi_r = FDIM + layer * FF;
    const float2* ew = g_ew + layer * NR;
    int s0 = g_rowptr[n], s1 = g_rowptr[n + 1];
    float* oe = buf + (size_t)n * OD + bi_e + FF;
    float* orp = buf + (size_t)n * OD + bi_r + FF;
    if (s1 == s0) {
        if (g16 == 0) {
            *(float4*)(oe + 8 * li) = make_float4(0.f, 0.f, 0.f, 0.f);
            *(float4*)(oe + 8 * li + 4) = make_float4(0.f, 0.f, 0.f, 0.f);
            *(float4*)(orp + 8 * li) = make_float4(0.f, 0.f, 0.f, 0.f);
            *(float4*)(orp + 8 * li + 4) = make_float4(0.f, 0.f, 0.f, 0.f);
        }
        return;
    }
    float4 aeA = {0,0,0,0}, aeB = {0,0,0,0}, arA = {0,0,0,0}, arB = {0,0,0,0};
    float wse = 0.f, wsr = 0.f;
    for (int idx = s0; idx < s1; idx += 4) {
        int e = idx + g16;
        bool act = e < s1;
        u32 pk = g_csr[act ? e : s0];
        int s = (int)(pk >> 16), r = (int)(pk & 0xFFFFu);
        const float* hb = buf + (size_t)s * OD;
        float4 he0 = *(const float4*)(hb + bi_e + 8 * li);
        float4 he1 = *(const float4*)(hb + bi_e + 8 * li + 4);
        float4 hr0 = *(const float4*)(hb + bi_r + 8 * li);
        float4 hr1 = *(const float4*)(hb + bi_r + 8 * li + 4);
        const float* rp = g_relnorm + (size_t)r * FF + 8 * li;
        float4 rn0 = *(const float4*)rp;
        float4 rn1 = *(const float4*)(rp + 4);
        float de = he0.x * rn0.x + he0.y * rn0.y + he0.z * rn0.z + he0.w * rn0.w
                 + he1.x * rn1.x + he1.y * rn1.y + he1.z * rn1.z + he1.w * rn1.w;
        float dr = hr0.x * rn0.x + hr0.y * rn0.y + hr0.z * rn0.z + hr0.w * rn0.w
                 + hr1.x * rn1.x + hr1.y * rn1.y + hr1.z * rn1.z + hr1.w * rn1.w;
        red16x2(de, dr);
        float2 wv = act ? ew[r] : make_float2(0.f, 0.f);
        wse += wv.x; wsr += wv.y;
        float te = -2.f * de, tr = -2.f * dr;
        aeA.x = fmaf(wv.x, fmaf(te, rn0.x, he0.x), aeA.x);
        aeA.y = fmaf(wv.x, fmaf(te, rn0.y, he0.y), aeA.y);
        aeA.z = fmaf(wv.x, fmaf(te, rn0.z, he0.z), aeA.z);
        aeA.w = fmaf(wv.x, fmaf(te, rn0.w, he0.w), aeA.w);
        aeB.x = fmaf(wv.x, fmaf(te, rn1.x, he1.x), aeB.x);
        aeB.y = fmaf(wv.x, fmaf(te, rn1.y, he1.y), aeB.y);
        aeB.z = fmaf(wv.x, fmaf(te, rn1.z, he1.z), aeB.z);
        aeB.w = fmaf(wv.x, fmaf(te, rn1.w, he1.w), aeB.w);
        arA.x = fmaf(wv.y, fmaf(tr, rn0.x, hr0.x), arA.x);
        arA.y = fmaf(wv.y, fmaf(tr, rn0.y, hr0.y), arA.y);
        arA.z = fmaf(wv.y, fmaf(tr, rn0.z, hr0.z), arA.z);
        arA.w = fmaf(wv.y, fmaf(tr, rn0.w, hr0.w), arA.w);
        arB.x = fmaf(wv.y, fmaf(tr, rn1.x, hr1.x), arB.x);
        arB.y = fmaf(wv.y, fmaf(tr, rn1.y, hr1.y), arB.y);
        arB.z = fmaf(wv.y, fmaf(tr, rn1.z, hr1.z), arB.z);
        arB.w = fmaf(wv.y, fmaf(tr, rn1.w, hr1.w), arB.w);
    }
    xgr4(aeA); xgr4(aeB); xgr4(arA); xgr4(arB);
    xgr1(wse); xgr1(wsr);
    float ive = 1.f / wse, ivr = 1.f / wsr;
    if (g16 == 0) {
        *(float4*)(oe + 8 * li) = make_float4(tanhf(aeA.x * ive), tanhf(aeA.y * ive),
                                              tanhf(aeA.z * ive), tanhf(aeA.w * ive));
        *(float4*)(oe + 8 * li + 4) = make_float4(tanhf(aeB.x * ive), tanhf(aeB.y * ive),
                                                  tanhf(aeB.z * ive), tanhf(aeB.w * ive));
        *(float4*)(orp + 8 * li) = make_float4(tanhf(arA.x * ivr), tanhf(arA.y * ivr),
                                               tanhf(arA.z * ivr), tanhf(arA.w * ivr));
        *(float4*)(orp + 8 * li + 4) = make_float4(tanhf(arB.x * ivr), tanhf(arB.y * ivr),
                                                   tanhf(arB.z * ivr), tanhf(arB.w * ivr));
    }
}

// --- fused proxy attention + gate, MFMA (round-2 winner): 32 nodes/block ---
__global__ __launch_bounds__(256, 2) void k_pg(
    float* out, const float* __restrict__ bias_e,
    const float* __restrict__ bias_r) {
    __shared__ __attribute__((aligned(16))) u32 o_pk[NPB * FSTR];   // 49.7 KB
    __shared__ __attribute__((aligned(16))) u32 att_pk[NPB * ASTR]; // 8.7 KB
    __shared__ float invn_s[NPB];
    int tid = threadIdx.x;
    int lane = tid & 63, w = tid >> 6;
    int c = lane & 15, kg = lane >> 4;   // MFMA fragment coords
    int n0 = blockIdx.x * NPB, dual = blockIdx.y;
    int dual_off = dual * FDIM;
    const float* bias = dual ? bias_r : bias_e;
    const u16* wt_h = g_wt_hi + dual * (FDIM * FDIM);
    const u16* wt_l = g_wt_lo + dual * (FDIM * FDIM);
    const u16* pn_h = g_pxn_hi + dual * (PP * FDIM);
    const u16* pn_l = g_pxn_lo + dual * (PP * FDIM);
    const u16* pt_h = g_pxT_hi + dual * (FDIM * PP);
    const u16* pt_l = g_pxT_lo + dual * (FDIM * PP);

    // ---- phase 1: stage + sumsq + pack in one pass (wave w: rows w+4j) ----
#pragma unroll
    for (int j = 0; j < 8; j++) {
        int n = w + 4 * j;
        int gn = n0 + n;
        float2 v[3];
        if (gn < NN) {
            const float* rp = out + (size_t)gn * OD + dual_off;
#pragma unroll
            for (int q = 0; q < 3; q++) v[q] = *(const float2*)(rp + 2 * (lane + 64 * q));
        } else {
            v[0] = v[1] = v[2] = make_float2(0.f, 0.f);
        }
        float ss = 0.f;
#pragma unroll
        for (int q = 0; q < 3; q++) ss += v[q].x * v[q].x + v[q].y * v[q].y;
        ss = wsum64(ss);
        if (lane == 0) invn_s[n] = 1.f / fmaxf(sqrtf(ss), NEPS);
#pragma unroll
        for (int q = 0; q < 3; q++) {
            uint2 pr;
            pr.x = pack_bf(v[q].x);
            pr.y = pack_bf(v[q].y);
            *(uint2*)(o_pk + n * FSTR + 2 * (lane + 64 * q)) = pr;
        }
    }
    __syncthreads();

    // ---- phase 2: logits = (o @ l2n(proxy)^T)*invn; wave w -> p-tile, both m ----
    {
        f32x4 lacc[2] = {{0.f,0.f,0.f,0.f},{0.f,0.f,0.f,0.f}};
        const u16* bh_p = pn_h + (16 * w + c) * FDIM;
        const u16* bl_p = pn_l + (16 * w + c) * FDIM;
#pragma unroll 2
        for (int ks = 0; ks < 12; ks++) {
            int kb = 32 * ks + 8 * kg;
            bf16x8 bh = *(const bf16x8*)(bh_p + kb);
            bf16x8 bl = *(const bf16x8*)(bl_p + kb);
#pragma unroll
            for (int m = 0; m < 2; m++) {
                bf16x8 ah, al;
                load_afrag(o_pk + (16 * m + c) * FSTR + kb, ah, al);
                lacc[m] = __builtin_amdgcn_mfma_f32_16x16x32_bf16(ah, bh, lacc[m], 0, 0, 0);
                lacc[m] = __builtin_amdgcn_mfma_f32_16x16x32_bf16(al, bh, lacc[m], 0, 0, 0);
                lacc[m] = __builtin_amdgcn_mfma_f32_16x16x32_bf16(ah, bl, lacc[m], 0, 0, 0);
            }
        }
#pragma unroll
        for (int m = 0; m < 2; m++)
#pragma unroll
            for (int i = 0; i < 4; i++) {
                int n = 16 * m + 4 * kg + i;
                att_pk[n * ASTR + 16 * w + c] = __float_as_uint(lacc[m][i] * invn_s[n]);
            }
    }
    __syncthreads();

    // ---- phase 3: softmax over P=64 + pack, one pass ----
#pragma unroll
    for (int j = 0; j < 8; j++) {
        int n = w + 4 * j;
        float l = __uint_as_float(att_pk[n * ASTR + lane]);
        float mx = wmax64(l);
        float e = expf(l - mx);
        float s = wsum64(e);
        att_pk[n * ASTR + lane] = pack_bf(e / s);
    }
    __syncthreads();

    // ---- phase 4: pf = o - att @ proxy (K=64); repack pf over o in place ----
    f32x4 pacc[2][6];
#pragma unroll
    for (int m = 0; m < 2; m++)
#pragma unroll
        for (int t = 0; t < 6; t++) pacc[m][t] = (f32x4){0.f, 0.f, 0.f, 0.f};
    {
        bf16x8 aah[2][2], aal[2][2];   // [m][k-half]
#pragma unroll
        for (int m = 0; m < 2; m++) {
            load_afrag(att_pk + (16 * m + c) * ASTR + 8 * kg, aah[m][0], aal[m][0]);
            load_afrag(att_pk + (16 * m + c) * ASTR + 32 + 8 * kg, aah[m][1], aal[m][1]);
        }
#pragma unroll
        for (int t = 0; t < 6; t++) {
            int f = 96 * w + 16 * t + c;
            const u16* bh0 = pt_h + f * PP;
            const u16* bl0 = pt_l + f * PP;
            bf16x8 b0h = *(const bf16x8*)(bh0 + 8 * kg);
            bf16x8 b0l = *(const bf16x8*)(bl0 + 8 * kg);
            bf16x8 b1h = *(const bf16x8*)(bh0 + 32 + 8 * kg);
            bf16x8 b1l = *(const bf16x8*)(bl0 + 32 + 8 * kg);
#pragma unroll
            for (int m = 0; m < 2; m++) {
                pacc[m][t] = __builtin_amdgcn_mfma_f32_16x16x32_bf16(aah[m][0], b0h, pacc[m][t], 0, 0, 0);
                pacc[m][t] = __builtin_amdgcn_mfma_f32_16x16x32_bf16(aal[m][0], b0h, pacc[m][t], 0, 0, 0);
                pacc[m][t] = __builtin_amdgcn_mfma_f32_16x16x32_bf16(aah[m][0], b0l, pacc[m][t], 0, 0, 0);
                pacc[m][t] = __builtin_amdgcn_mfma_f32_16x16x32_bf16(aah[m][1], b1h, pacc[m][t], 0, 0, 0);
                pacc[m][t] = __builtin_amdgcn_mfma_f32_16x16x32_bf16(aal[m][1], b1h, pacc[m][t], 0, 0, 0);
                pacc[m][t] = __builtin_amdgcn_mfma_f32_16x16x32_bf16(aah[m][1], b1l, pacc[m][t], 0, 0, 0);
            }
        }
        // pf write-back (packed); each thread owns its (n,f) cells
#pragma unroll
        for (int t = 0; t < 6; t++) {
            int f = 96 * w + 16 * t + c;
#pragma unroll
            for (int m = 0; m < 2; m++)
#pragma unroll
                for (int i = 0; i < 4; i++) {
                    int n = 16 * m + 4 * kg + i;
                    u32 pk = o_pk[n * FSTR + f];
                    o_pk[n * FSTR + f] = pack_bf(unpack_bf(pk) - pacc[m][t][i]);
                }
        }
    }
    __syncthreads();

    // ---- phase 5: gate GEMM lin = pf @ W, register-pipelined B loads ----
    f32x4 gacc[2][6];
#pragma unroll
    for (int m = 0; m < 2; m++)
#pragma unroll
        for (int t = 0; t < 6; t++) gacc[m][t] = (f32x4){0.f, 0.f, 0.f, 0.f};
    {
        const u16* wtw_h = wt_h + (96 * w + c) * FDIM;
        const u16* wtw_l = wt_l + (96 * w + c) * FDIM;
#pragma unroll 2
        for (int ks = 0; ks < 12; ks++) {
            int kb = 32 * ks + 8 * kg;
            bf16x8 bhv[6], blv[6];
#pragma unroll
            for (int t = 0; t < 6; t++) {
                bhv[t] = *(const bf16x8*)(wtw_h + t * 16 * FDIM + kb);
                blv[t] = *(const bf16x8*)(wtw_l + t * 16 * FDIM + kb);
            }
            bf16x8 ah[2], al[2];
#pragma unroll
            for (int m = 0; m < 2; m++)
                load_afrag(o_pk + (16 * m + c) * FSTR + kb, ah[m], al[m]);
#pragma unroll
            for (int t = 0; t < 6; t++)
#pragma unroll
                for (int m = 0; m < 2; m++) {
                    gacc[m][t] = __builtin_amdgcn_mfma_f32_16x16x32_bf16(ah[m], bhv[t], gacc[m][t], 0, 0, 0);
                    gacc[m][t] = __builtin_amdgcn_mfma_f32_16x16x32_bf16(al[m], bhv[t], gacc[m][t], 0, 0, 0);
                    gacc[m][t] = __builtin_amdgcn_mfma_f32_16x16x32_bf16(ah[m], blv[t], gacc[m][t], 0, 0, 0);
                }
        }
    }

    // ---- epilogue: gt = sigmoid(lin+bias); o = pf + pacc; out = gt*o + (1-gt)*pf ----
#pragma unroll
    for (int t = 0; t < 6; t++) {
        int fcol = 96 * w + 16 * t + c;
        float b = bias[fcol];
#pragma unroll
        for (int m = 0; m < 2; m++)
#pragma unroll
            for (int i = 0; i < 4; i++) {
                int n = 16 * m + 4 * kg + i;
                int gn = n0 + n;
                if (gn < NN) {
                    float lin = gacc[m][t][i] + b;
                    float gt = 1.f / (1.f + expf(-lin));
                    float pv = unpack_bf(o_pk[n * FSTR + fcol]);
                    float ov = pv + pacc[m][t][i];
                    out[(size_t)gn * OD + dual_off + fcol] = gt * ov + (1.f - gt) * pv;
                }
            }
    }
}

extern "C" void kernel_launch(void* const* d_in, const int* in_sizes, int n_in,
                              void* d_out, int out_size, void* d_ws, size_t ws_size,
                              hipStream_t stream) {
    const float* ent_emb = (const float*)d_in[0];
    const float* rel_emb = (const float*)d_in[1];
    const int* e_src     = (const int*)d_in[2];
    const int* e_dst     = (const int*)d_in[3];
    const int* e_rel     = (const int*)d_in[4];
    const float* attn_e  = (const float*)d_in[5];
    const float* gate_e  = (const float*)d_in[6];
    const float* proxy_e = (const float*)d_in[7];
    const float* bias_e  = (const float*)d_in[8];
    const float* attn_r  = (const float*)d_in[9];
    const float* gate_r  = (const float*)d_in[10];
    const float* proxy_r = (const float*)d_in[11];
    const float* bias_r  = (const float*)d_in[12];
    float* out = (float*)d_out;
    (void)d_ws; (void)ws_size; (void)in_sizes; (void)n_in; (void)out_size;

    k_zero<<<(NN + 255) / 256, 256, 0, stream>>>();
    k_prep_rel<<<NR / 4, 256, 0, stream>>>(rel_emb, attn_e, attn_r);
    k_prep_proxy<<<32, 256, 0, stream>>>(proxy_e, proxy_r);
    k_prep_wt<<<(2 * FDIM * FDIM + 255) / 256, 256, 0, stream>>>(gate_e, gate_r);
    k_count<<<(NE + 255) / 256, 256, 0, stream>>>(e_dst);
    k_scan1<<<NBLK, 1024, 0, stream>>>();
    k_scan2<<<1, 64, 0, stream>>>();
    k_scan3<<<NBLK, 1024, 0, stream>>>();
    k_fill<<<(NE + 255) / 256, 256, 0, stream>>>(e_src, e_dst, e_rel);
    k_init<<<NN / 4, 256, 0, stream>>>(ent_emb, rel_emb, out);
    k_layer<<<NN / 4, 256, 0, stream>>>(out, 0);
    k_layer<<<NN / 4, 256, 0, stream>>>(out, 1);
    k_pg<<<dim3((NN + NPB - 1) / NPB, 2), 256, 0, stream>>>(out, bias_e, bias_r);
}

// Round 5
// 866.120 us; speedup vs baseline: 1.9654x; 1.1744x over previous
//
#include <hip/hip_runtime.h>
#include <math.h>

// ---------------------------------------------------------------------------
// overAll_37606733644133 : relational GNN (2-layer Householder-reflection
// message passing with edge softmax) + proxy attention + gated mixing.
//
// Round-5:
//  - fp16 gather path: features duplicated into compact fp16 slabs
//    g_hh[layer][N][256] (both duals contiguous) and ent_emb pre-converted
//    to fp16 (g_ent16). k_init/k_layer gather fp16 (half the bytes of the
//    bandwidth-bound random gather), compute fp32, write canonical fp32 out.
//    k_pg still stages from fp32 out (no precision change there).
//  - k_pg: phase-1/3 wave reductions batched 8-wide (one interleaved
//    shuffle cascade instead of 8 serial chains); softmax max-pass dropped
//    (logits are cosines in [-1,1]; exp shift-invariant).
//  - keeps: round-2 k_pg GEMM structure, fused-dual k_layer, g_ew exp
//    table, hierarchical scan.
// ---------------------------------------------------------------------------

#define NN    50000
#define NE    800000
#define NR    2000
#define FF    128
#define FDIM  384
#define OD    768     // output row stride (2 duals x 384)
#define PP    64
#define NEPS  1e-12f
#define NPB   32      // nodes per k_pg block
#define FSTR  388     // LDS row stride (u32) for o/pf tile: 388%32=4 -> 2-way (free)
#define ASTR  68      // LDS row stride (u32) for att tile:  68%32=4 -> 2-way (free)
#define NBLK  49      // scan blocks: ceil(50000/1024)

typedef unsigned int u32;
typedef unsigned short u16;
typedef __attribute__((ext_vector_type(8))) short bf16x8;     // 8 bf16 (4 VGPRs)
typedef __attribute__((ext_vector_type(8))) _Float16 f16x8;   // 8 fp16 (4 VGPRs)
typedef __attribute__((ext_vector_type(4))) float f32x4;

// ---- static device scratch ------------------------------------------------
__device__ int   g_rowptr[NN + 1];
__device__ int   g_cnt[NN];
__device__ int   g_bsum[64];
__device__ u32   g_csr[NE];               // (src<<16) | rel
__device__ float g_relnorm[NR * FF];
__device__ float2 g_ew[2 * NR];           // [layer][r] = (exp(atab_ent), exp(atab_rel))
// fp16 gather slabs: [slab][n][0..128)=ent feats, [128..256)=rel feats
__device__ __attribute__((aligned(16))) _Float16 g_hh[2][NN][256];   // 51.2 MB
__device__ __attribute__((aligned(16))) _Float16 g_ent16[NN * FF];   // 12.8 MB
// split-bf16 B-operands, all n-major / k-contiguous:
__device__ __attribute__((aligned(16))) u16 g_wt_hi[2 * FDIM * FDIM];  // [d][f][k] = W_d[k][f]
__device__ __attribute__((aligned(16))) u16 g_wt_lo[2 * FDIM * FDIM];
__device__ __attribute__((aligned(16))) u16 g_pxn_hi[2 * PP * FDIM];   // [d][p][k] = l2n(proxy_d[p])[k]
__device__ __attribute__((aligned(16))) u16 g_pxn_lo[2 * PP * FDIM];
__device__ __attribute__((aligned(16))) u16 g_pxT_hi[2 * FDIM * PP];   // [d][f][p] = proxy_d[p][f]
__device__ __attribute__((aligned(16))) u16 g_pxT_lo[2 * FDIM * PP];

__device__ __forceinline__ float wsum64(float v) {
#pragma unroll
    for (int m = 32; m > 0; m >>= 1) v += __shfl_xor(v, m, 64);
    return v;
}
// 16-lane-group sum (masks 1,2,4,8), two values interleaved
__device__ __forceinline__ void red16x2(float& a, float& b) {
#pragma unroll
    for (int m = 1; m < 16; m <<= 1) {
        float ta = __shfl_xor(a, m, 64);
        float tb = __shfl_xor(b, m, 64);
        a += ta; b += tb;
    }
}

// fp32 -> (bf16_hi << 16) | bf16_lo, both RNE; hi+lo reconstructs to ~2^-16 rel
__device__ __forceinline__ u32 pack_bf(float f) {
    u32 x = __float_as_uint(f);
    u32 hr = (x + 0x7FFFu + ((x >> 16) & 1u)) & 0xFFFF0000u;
    float res = f - __uint_as_float(hr);
    u32 y = __float_as_uint(res);
    u32 lr = (y + 0x7FFFu + ((y >> 16) & 1u)) >> 16;
    return hr | lr;
}
__device__ __forceinline__ float unpack_bf(u32 pk) {
    return __uint_as_float(pk & 0xFFFF0000u) + __uint_as_float(pk << 16);
}

// read 8 packed elems (32B, 2x ds_read_b128) -> hi / lo bf16x8 fragments
__device__ __forceinline__ void load_afrag(const u32* p, bf16x8& ah, bf16x8& al) {
    u32 q[8];
    *reinterpret_cast<float4*>(q)     = *reinterpret_cast<const float4*>(p);
    *reinterpret_cast<float4*>(q + 4) = *reinterpret_cast<const float4*>(p + 4);
    union { u32 u[4]; bf16x8 v; } H, L;
#pragma unroll
    for (int j = 0; j < 4; j++) {
        H.u[j] = __builtin_amdgcn_perm(q[2 * j + 1], q[2 * j], 0x07060302u);
        L.u[j] = __builtin_amdgcn_perm(q[2 * j + 1], q[2 * j], 0x05040100u);
    }
    ah = H.v; al = L.v;
}

__global__ __launch_bounds__(256) void k_zero() {
    int i = blockIdx.x * 256 + threadIdx.x;
    if (i < NN) g_cnt[i] = 0;
}

// --- relnorm[r] = l2norm(rel_emb[r]); g_ew[l][r] = exp(relnorm.attn) both duals ---
__global__ __launch_bounds__(256) void k_prep_rel(
    const float* __restrict__ rel_emb, const float* __restrict__ attn_e,
    const float* __restrict__ attn_r) {
    int wave = threadIdx.x >> 6, lane = threadIdx.x & 63;
    int r = blockIdx.x * 4 + wave;
    if (r >= NR) return;
    float2 v = *(const float2*)(rel_emb + r * FF + 2 * lane);
    float ss = wsum64(v.x * v.x + v.y * v.y);
    float inv = 1.f / fmaxf(sqrtf(ss), NEPS);
    float rn0 = v.x * inv, rn1 = v.y * inv;
    *(float2*)(g_relnorm + r * FF + 2 * lane) = make_float2(rn0, rn1);
#pragma unroll
    for (int t = 0; t < 4; t++) {   // t = dual*2 + layer
        const float* av = ((t < 2) ? attn_e : attn_r) + (t & 1) * FF + 2 * lane;
        float d = wsum64(rn0 * av[0] + rn1 * av[1]);
        if (lane == 0) ((float*)&g_ew[(t & 1) * NR + r])[t >> 1] = expf(d);
    }
}

// --- ent_emb -> fp16 table for the k_init gather ---
__global__ __launch_bounds__(256) void k_prep_ent(const float* __restrict__ ent_emb) {
    int i = (blockIdx.x * 256 + threadIdx.x) * 8;
    if (i >= NN * FF) return;
    float4 a = *(const float4*)(ent_emb + i);
    float4 b = *(const float4*)(ent_emb + i + 4);
    f16x8 h;
    h[0] = (_Float16)a.x; h[1] = (_Float16)a.y; h[2] = (_Float16)a.z; h[3] = (_Float16)a.w;
    h[4] = (_Float16)b.x; h[5] = (_Float16)b.y; h[6] = (_Float16)b.z; h[7] = (_Float16)b.w;
    *(f16x8*)(g_ent16 + i) = h;
}

// --- split-bf16 proxy tables: l2n rows ([d][p][k]) and raw transpose ([d][f][p]) ---
__global__ __launch_bounds__(256) void k_prep_proxy(
    const float* __restrict__ proxy_e, const float* __restrict__ proxy_r) {
    int wave = threadIdx.x >> 6, lane = threadIdx.x & 63;
    int row = blockIdx.x * 4 + wave;  // 0..127
    if (row >= 2 * PP) return;
    int d = row >> 6, p = row & 63;
    const float* pr = ((d == 0) ? proxy_e : proxy_r) + p * FDIM;
    float v[6];
    float ss = 0.f;
#pragma unroll
    for (int j = 0; j < 6; j++) {
        v[j] = pr[lane + 64 * j];
        ss += v[j] * v[j];
    }
    ss = wsum64(ss);
    float inv = 1.f / fmaxf(sqrtf(ss), NEPS);
#pragma unroll
    for (int j = 0; j < 6; j++) {
        int k = lane + 64 * j;
        u32 pn = pack_bf(v[j] * inv);
        g_pxn_hi[(d * PP + p) * FDIM + k] = (u16)(pn >> 16);
        g_pxn_lo[(d * PP + p) * FDIM + k] = (u16)(pn & 0xFFFFu);
        u32 pt = pack_bf(v[j]);
        g_pxT_hi[(d * FDIM + k) * PP + p] = (u16)(pt >> 16);
        g_pxT_lo[(d * FDIM + k) * PP + p] = (u16)(pt & 0xFFFFu);
    }
}

// --- split-bf16 gate weights, transposed: wt[d][f][k] = W_d[k][f] ---
__global__ __launch_bounds__(256) void k_prep_wt(
    const float* __restrict__ gate_e, const float* __restrict__ gate_r) {
    int idx = blockIdx.x * 256 + threadIdx.x;
    if (idx >= 2 * FDIM * FDIM) return;
    int d = idx / (FDIM * FDIM);
    int rem = idx - d * (FDIM * FDIM);
    int k = rem / FDIM;
    int f = rem - k * FDIM;          // consecutive lanes -> consecutive f: coalesced read
    float wv = (d ? gate_r : gate_e)[k * FDIM + f];
    u32 pk = pack_bf(wv);
    g_wt_hi[(d * FDIM + f) * FDIM + k] = (u16)(pk >> 16);
    g_wt_lo[(d * FDIM + f) * FDIM + k] = (u16)(pk & 0xFFFFu);
}

__global__ __launch_bounds__(256) void k_count(const int* __restrict__ dst) {
    int e = blockIdx.x * 256 + threadIdx.x;
    if (e < NE) atomicAdd(&g_cnt[dst[e]], 1);
}

// --- hierarchical exclusive scan: per-block scan -> block-sum scan -> add ---
__global__ __launch_bounds__(1024) void k_scan1() {
    __shared__ int s[1024];
    int b = blockIdx.x, tid = threadIdx.x;
    int i = b * 1024 + tid;
    int v = (i < NN) ? g_cnt[i] : 0;
    s[tid] = v;
    __syncthreads();
    for (int off = 1; off < 1024; off <<= 1) {
        int t = (tid >= off) ? s[tid - off] : 0;
        __syncthreads();
        s[tid] += t;
        __syncthreads();
    }
    if (i < NN) {
        g_rowptr[i] = s[tid] - v;   // exclusive within block
        g_cnt[i] = 0;
    }
    if (tid == 1023) g_bsum[b] = s[1023];
}
__global__ __launch_bounds__(64) void k_scan2() {
    int lane = threadIdx.x;
    int v = (lane < NBLK) ? g_bsum[lane] : 0;
#pragma unroll
    for (int off = 1; off < 64; off <<= 1) {
        int t = __shfl_up(v, off, 64);
        if (lane >= off) v += t;
    }
    if (lane < NBLK) g_bsum[lane] = v;  // inclusive block-sum scan
    if (lane == 0) g_rowptr[NN] = NE;
}
__global__ __launch_bounds__(1024) void k_scan3() {
    int b = blockIdx.x;
    if (b == 0) return;
    int i = b * 1024 + threadIdx.x;
    if (i < NN) g_rowptr[i] += g_bsum[b - 1];
}

__global__ __launch_bounds__(256) void k_fill(
    const int* __restrict__ src, const int* __restrict__ dst,
    const int* __restrict__ rel) {
    int e = blockIdx.x * 256 + threadIdx.x;
    if (e >= NE) return;
    int d = dst[e];
    int pos = atomicAdd(&g_cnt[d], 1);
    g_csr[g_rowptr[d] + pos] = ((u32)src[e] << 16) | (u32)rel[e];
}

// --- initial features: tanh(mean over incoming edges), both duals ---
// 4 edges/wave (16-lane groups), 8 features/lane; ent gathered fp16.
__global__ __launch_bounds__(256) void k_init(
    const float* __restrict__ rel_emb, float* __restrict__ out) {
    int wave = threadIdx.x >> 6, lane = threadIdx.x & 63;
    int n = blockIdx.x * 4 + wave;
    if (n >= NN) return;
    int g16 = lane >> 4, li = lane & 15;
    int s0 = g_rowptr[n], s1 = g_rowptr[n + 1];
    float ae[8], ar[8];
#pragma unroll
    for (int i = 0; i < 8; i++) { ae[i] = 0.f; ar[i] = 0.f; }
    for (int idx = s0; idx < s1; idx += 4) {
        int e = idx + g16;
        if (e < s1) {
            u32 pk = g_csr[e];
            int s = (int)(pk >> 16), r = (int)(pk & 0xFFFFu);
            f16x8 ev = *(const f16x8*)(g_ent16 + (size_t)s * FF + 8 * li);
            const float* rp = rel_emb + (size_t)r * FF + 8 * li;
            float4 r0 = *(const float4*)rp, r1 = *(const float4*)(rp + 4);
            float rv[8] = {r0.x, r0.y, r0.z, r0.w, r1.x, r1.y, r1.z, r1.w};
#pragma unroll
            for (int i = 0; i < 8; i++) {
                ae[i] += (float)ev[i];
                ar[i] += rv[i];
            }
        }
    }
#pragma unroll
    for (int mk = 16; mk < 64; mk <<= 1)
#pragma unroll
        for (int i = 0; i < 8; i++) {
            ae[i] += __shfl_xor(ae[i], mk, 64);
            ar[i] += __shfl_xor(ar[i], mk, 64);
        }
    float invd = 1.f / (float)max(s1 - s0, 1);
    if (g16 == 0) {
        float fe[8], fr[8];
#pragma unroll
        for (int i = 0; i < 8; i++) {
            fe[i] = tanhf(ae[i] * invd);
            fr[i] = tanhf(ar[i] * invd);
        }
        float* oe = out + (size_t)n * OD + 8 * li;
        float* orp = out + (size_t)n * OD + FDIM + 8 * li;
        *(float4*)oe = make_float4(fe[0], fe[1], fe[2], fe[3]);
        *(float4*)(oe + 4) = make_float4(fe[4], fe[5], fe[6], fe[7]);
        *(float4*)orp = make_float4(fr[0], fr[1], fr[2], fr[3]);
        *(float4*)(orp + 4) = make_float4(fr[4], fr[5], fr[6], fr[7]);
        _Float16* hh = &g_hh[0][n][0];
        f16x8 he, hr;
#pragma unroll
        for (int i = 0; i < 8; i++) { he[i] = (_Float16)fe[i]; hr[i] = (_Float16)fr[i]; }
        *(f16x8*)(hh + 8 * li) = he;
        *(f16x8*)(hh + 128 + 8 * li) = hr;
    }
}

// --- one message-passing layer, BOTH duals fused, 4 edges/wave ---
// gathers fp16 compact slab g_hh[layer] (512B/edge), computes fp32, writes
// fp32 out + (layer 0 only) fp16 slab for the next layer's gather.
__global__ __launch_bounds__(256) void k_layer(float* buf, int layer) {
    int wave = threadIdx.x >> 6, lane = threadIdx.x & 63;
    int n = blockIdx.x * 4 + wave;
    if (n >= NN) return;
    int g16 = lane >> 4, li = lane & 15;
    int bo_e = (layer + 1) * FF;          // output cols, ent block
    int bo_r = FDIM + (layer + 1) * FF;   // output cols, rel block
    const float2* ew = g_ew + layer * NR;
    const _Float16* hs = &g_hh[layer][0][0];
    int s0 = g_rowptr[n], s1 = g_rowptr[n + 1];
    if (s1 == s0) {
        if (g16 == 0) {
            float* oe = buf + (size_t)n * OD + bo_e + 8 * li;
            float* orp = buf + (size_t)n * OD + bo_r + 8 * li;
            *(float4*)oe = make_float4(0.f, 0.f, 0.f, 0.f);
            *(float4*)(oe + 4) = make_float4(0.f, 0.f, 0.f, 0.f);
            *(float4*)orp = make_float4(0.f, 0.f, 0.f, 0.f);
            *(float4*)(orp + 4) = make_float4(0.f, 0.f, 0.f, 0.f);
            if (layer == 0) {
                _Float16* hh = &g_hh[1][n][0];
                f16x8 z = (f16x8)(_Float16)0.f;
                *(f16x8*)(hh + 8 * li) = z;
                *(f16x8*)(hh + 128 + 8 * li) = z;
            }
        }
        return;
    }
    float ae[8], ar[8];
#pragma unroll
    for (int i = 0; i < 8; i++) { ae[i] = 0.f; ar[i] = 0.f; }
    float wse = 0.f, wsr = 0.f;
    for (int idx = s0; idx < s1; idx += 4) {
        int e = idx + g16;
        bool act = e < s1;
        u32 pk = g_csr[act ? e : s0];
        int s = (int)(pk >> 16), r = (int)(pk & 0xFFFFu);
        const _Float16* hrow = hs + (size_t)s * 256;
        f16x8 hev = *(const f16x8*)(hrow + 8 * li);
        f16x8 hrv = *(const f16x8*)(hrow + 128 + 8 * li);
        const float* rp = g_relnorm + (size_t)r * FF + 8 * li;
        float4 rn0 = *(const float4*)rp;
        float4 rn1 = *(const float4*)(rp + 4);
        float rnv[8] = {rn0.x, rn0.y, rn0.z, rn0.w, rn1.x, rn1.y, rn1.z, rn1.w};
        float he[8], hr[8];
#pragma unroll
        for (int i = 0; i < 8; i++) { he[i] = (float)hev[i]; hr[i] = (float)hrv[i]; }
        float de = 0.f, dr = 0.f;
#pragma unroll
        for (int i = 0; i < 8; i++) {
            de = fmaf(he[i], rnv[i], de);
            dr = fmaf(hr[i], rnv[i], dr);
        }
        red16x2(de, dr);
        float2 wv = act ? ew[r] : make_float2(0.f, 0.f);
        wse += wv.x; wsr += wv.y;
        float te = -2.f * de, tr = -2.f * dr;
#pragma unroll
        for (int i = 0; i < 8; i++) {
            ae[i] = fmaf(wv.x, fmaf(te, rnv[i], he[i]), ae[i]);
            ar[i] = fmaf(wv.y, fmaf(tr, rnv[i], hr[i]), ar[i]);
        }
    }
#pragma unroll
    for (int mk = 16; mk < 64; mk <<= 1) {
#pragma unroll
        for (int i = 0; i < 8; i++) {
            ae[i] += __shfl_xor(ae[i], mk, 64);
            ar[i] += __shfl_xor(ar[i], mk, 64);
        }
        wse += __shfl_xor(wse, mk, 64);
        wsr += __shfl_xor(wsr, mk, 64);
    }
    float ive = 1.f / wse, ivr = 1.f / wsr;
    if (g16 == 0) {
        float fe[8], fr[8];
#pragma unroll
        for (int i = 0; i < 8; i++) {
            fe[i] = tanhf(ae[i] * ive);
            fr[i] = tanhf(ar[i] * ivr);
        }
        float* oe = buf + (size_t)n * OD + bo_e + 8 * li;
        float* orp = buf + (size_t)n * OD + bo_r + 8 * li;
        *(float4*)oe = make_float4(fe[0], fe[1], fe[2], fe[3]);
        *(float4*)(oe + 4) = make_float4(fe[4], fe[5], fe[6], fe[7]);
        *(float4*)orp = make_float4(fr[0], fr[1], fr[2], fr[3]);
        *(float4*)(orp + 4) = make_float4(fr[4], fr[5], fr[6], fr[7]);
        if (layer == 0) {
            _Float16* hh = &g_hh[1][n][0];
            f16x8 he16, hr16;
#pragma unroll
            for (int i = 0; i < 8; i++) { he16[i] = (_Float16)fe[i]; hr16[i] = (_Float16)fr[i]; }
            *(f16x8*)(hh + 8 * li) = he16;
            *(f16x8*)(hh + 128 + 8 * li) = hr16;
        }
    }
}

// --- fused proxy attention + gate, MFMA (round-2 structure + batched
//     reductions, no softmax max-pass): 32 nodes/block, y = dual ---
__global__ __launch_bounds__(256, 2) void k_pg(
    float* out, const float* __restrict__ bias_e,
    const float* __restrict__ bias_r) {
    __shared__ __attribute__((aligned(16))) u32 o_pk[NPB * FSTR];   // 49.7 KB
    __shared__ __attribute__((aligned(16))) u32 att_pk[NPB * ASTR]; // 8.7 KB
    __shared__ float invn_s[NPB];
    int tid = threadIdx.x;
    int lane = tid & 63, w = tid >> 6;
    int c = lane & 15, kg = lane >> 4;   // MFMA fragment coords
    int n0 = blockIdx.x * NPB, dual = blockIdx.y;
    int dual_off = dual * FDIM;
    const float* bias = dual ? bias_r : bias_e;
    const u16* wt_h = g_wt_hi + dual * (FDIM * FDIM);
    const u16* wt_l = g_wt_lo + dual * (FDIM * FDIM);
    const u16* pn_h = g_pxn_hi + dual * (PP * FDIM);
    const u16* pn_l = g_pxn_lo + dual * (PP * FDIM);
    const u16* pt_h = g_pxT_hi + dual * (FDIM * PP);
    const u16* pt_l = g_pxT_lo + dual * (FDIM * PP);

    // ---- phase 1: stage + batched sumsq + pack (wave w: rows w+4j) ----
    {
        float2 v[8][3];
        float ss[8];
#pragma unroll
        for (int j = 0; j < 8; j++) {
            int n = w + 4 * j;
            int gn = n0 + n;
            if (gn < NN) {
                const float* rp = out + (size_t)gn * OD + dual_off;
#pragma unroll
                for (int q = 0; q < 3; q++) v[j][q] = *(const float2*)(rp + 2 * (lane + 64 * q));
            } else {
                v[j][0] = v[j][1] = v[j][2] = make_float2(0.f, 0.f);
            }
            ss[j] = v[j][0].x * v[j][0].x + v[j][0].y * v[j][0].y
                  + v[j][1].x * v[j][1].x + v[j][1].y * v[j][1].y
                  + v[j][2].x * v[j][2].x + v[j][2].y * v[j][2].y;
        }
#pragma unroll
        for (int m = 32; m > 0; m >>= 1)
#pragma unroll
            for (int j = 0; j < 8; j++) ss[j] += __shfl_xor(ss[j], m, 64);
#pragma unroll
        for (int j = 0; j < 8; j++) {
            int n = w + 4 * j;
            if (lane == 0) invn_s[n] = 1.f / fmaxf(sqrtf(ss[j]), NEPS);
#pragma unroll
            for (int q = 0; q < 3; q++) {
                uint2 pr;
                pr.x = pack_bf(v[j][q].x);
                pr.y = pack_bf(v[j][q].y);
                *(uint2*)(o_pk + n * FSTR + 2 * (lane + 64 * q)) = pr;
            }
        }
    }
    __syncthreads();

    // ---- phase 2: logits = (o @ l2n(proxy)^T)*invn; wave w -> p-tile, both m ----
    {
        f32x4 lacc[2] = {{0.f,0.f,0.f,0.f},{0.f,0.f,0.f,0.f}};
        const u16* bh_p = pn_h + (16 * w + c) * FDIM;
        const u16* bl_p = pn_l + (16 * w + c) * FDIM;
#pragma unroll 2
        for (int ks = 0; ks < 12; ks++) {
            int kb = 32 * ks + 8 * kg;
            bf16x8 bh = *(const bf16x8*)(bh_p + kb);
            bf16x8 bl = *(const bf16x8*)(bl_p + kb);
#pragma unroll
            for (int m = 0; m < 2; m++) {
                bf16x8 ah, al;
                load_afrag(o_pk + (16 * m + c) * FSTR + kb, ah, al);
                lacc[m] = __builtin_amdgcn_mfma_f32_16x16x32_bf16(ah, bh, lacc[m], 0, 0, 0);
                lacc[m] = __builtin_amdgcn_mfma_f32_16x16x32_bf16(al, bh, lacc[m], 0, 0, 0);
                lacc[m] = __builtin_amdgcn_mfma_f32_16x16x32_bf16(ah, bl, lacc[m], 0, 0, 0);
            }
        }
#pragma unroll
        for (int m = 0; m < 2; m++)
#pragma unroll
            for (int i = 0; i < 4; i++) {
                int n = 16 * m + 4 * kg + i;
                att_pk[n * ASTR + 16 * w + c] = __float_as_uint(lacc[m][i] * invn_s[n]);
            }
    }
    __syncthreads();

    // ---- phase 3: softmax over P=64 (no max-pass: logits are cosines) ----
    {
        float ev[8], sv[8];
#pragma unroll
        for (int j = 0; j < 8; j++) {
            int n = w + 4 * j;
            ev[j] = expf(__uint_as_float(att_pk[n * ASTR + lane]));
            sv[j] = ev[j];
        }
#pragma unroll
        for (int m = 32; m > 0; m >>= 1)
#pragma unroll
            for (int j = 0; j < 8; j++) sv[j] += __shfl_xor(sv[j], m, 64);
#pragma unroll
        for (int j = 0; j < 8; j++) {
            int n = w + 4 * j;
            att_pk[n * ASTR + lane] = pack_bf(ev[j] / sv[j]);
        }
    }
    __syncthreads();

    // ---- phase 4: pf = o - att @ proxy (K=64); repack pf over o in place ----
    f32x4 pacc[2][6];
#pragma unroll
    for (int m = 0; m < 2; m++)
#pragma unroll
        for (int t = 0; t < 6; t++) pacc[m][t] = (f32x4){0.f, 0.f, 0.f, 0.f};
    {
        bf16x8 aah[2][2], aal[2][2];   // [m][k-half]
#pragma unroll
        for (int m = 0; m < 2; m++) {
            load_afrag(att_pk + (16 * m + c) * ASTR + 8 * kg, aah[m][0], aal[m][0]);
            load_afrag(att_pk + (16 * m + c) * ASTR + 32 + 8 * kg, aah[m][1], aal[m][1]);
        }
#pragma unroll
        for (int t = 0; t < 6; t++) {
            int f = 96 * w + 16 * t + c;
            const u16* bh0 = pt_h + f * PP;
            const u16* bl0 = pt_l + f * PP;
            bf16x8 b0h = *(const bf16x8*)(bh0 + 8 * kg);
            bf16x8 b0l = *(const bf16x8*)(bl0 + 8 * kg);
            bf16x8 b1h = *(const bf16x8*)(bh0 + 32 + 8 * kg);
            bf16x8 b1l = *(const bf16x8*)(bl0 + 32 + 8 * kg);
#pragma unroll
            for (int m = 0; m < 2; m++) {
                pacc[m][t] = __builtin_amdgcn_mfma_f32_16x16x32_bf16(aah[m][0], b0h, pacc[m][t], 0, 0, 0);
                pacc[m][t] = __builtin_amdgcn_mfma_f32_16x16x32_bf16(aal[m][0], b0h, pacc[m][t], 0, 0, 0);
                pacc[m][t] = __builtin_amdgcn_mfma_f32_16x16x32_bf16(aah[m][0], b0l, pacc[m][t], 0, 0, 0);
                pacc[m][t] = __builtin_amdgcn_mfma_f32_16x16x32_bf16(aah[m][1], b1h, pacc[m][t], 0, 0, 0);
                pacc[m][t] = __builtin_amdgcn_mfma_f32_16x16x32_bf16(aal[m][1], b1h, pacc[m][t], 0, 0, 0);
                pacc[m][t] = __builtin_amdgcn_mfma_f32_16x16x32_bf16(aah[m][1], b1l, pacc[m][t], 0, 0, 0);
            }
        }
        // pf write-back (packed); each thread owns its (n,f) cells
#pragma unroll
        for (int t = 0; t < 6; t++) {
            int f = 96 * w + 16 * t + c;
#pragma unroll
            for (int m = 0; m < 2; m++)
#pragma unroll
                for (int i = 0; i < 4; i++) {
                    int n = 16 * m + 4 * kg + i;
                    u32 pk = o_pk[n * FSTR + f];
                    o_pk[n * FSTR + f] = pack_bf(unpack_bf(pk) - pacc[m][t][i]);
                }
        }
    }
    __syncthreads();

    // ---- phase 5: gate GEMM lin = pf @ W, register-pipelined B loads ----
    f32x4 gacc[2][6];
#pragma unroll
    for (int m = 0; m < 2; m++)
#pragma unroll
        for (int t = 0; t < 6; t++) gacc[m][t] = (f32x4){0.f, 0.f, 0.f, 0.f};
    {
        const u16* wtw_h = wt_h + (96 * w + c) * FDIM;
        const u16* wtw_l = wt_l + (96 * w + c) * FDIM;
#pragma unroll 2
        for (int ks = 0; ks < 12; ks++) {
            int kb = 32 * ks + 8 * kg;
            bf16x8 bhv[6], blv[6];
#pragma unroll
            for (int t = 0; t < 6; t++) {
                bhv[t] = *(const bf16x8*)(wtw_h + t * 16 * FDIM + kb);
                blv[t] = *(const bf16x8*)(wtw_l + t * 16 * FDIM + kb);
            }
            bf16x8 ah[2], al[2];
#pragma unroll
            for (int m = 0; m < 2; m++)
                load_afrag(o_pk + (16 * m + c) * FSTR + kb, ah[m], al[m]);
#pragma unroll
            for (int t = 0; t < 6; t++)
#pragma unroll
                for (int m = 0; m < 2; m++) {
                    gacc[m][t] = __builtin_amdgcn_mfma_f32_16x16x32_bf16(ah[m], bhv[t], gacc[m][t], 0, 0, 0);
                    gacc[m][t] = __builtin_amdgcn_mfma_f32_16x16x32_bf16(al[m], bhv[t], gacc[m][t], 0, 0, 0);
                    gacc[m][t] = __builtin_amdgcn_mfma_f32_16x16x32_bf16(ah[m], blv[t], gacc[m][t], 0, 0, 0);
                }
        }
    }

    // ---- epilogue: gt = sigmoid(lin+bias); o = pf + pacc; out = gt*o + (1-gt)*pf ----
#pragma unroll
    for (int t = 0; t < 6; t++) {
        int fcol = 96 * w + 16 * t + c;
        float b = bias[fcol];
#pragma unroll
        for (int m = 0; m < 2; m++)
#pragma unroll
            for (int i = 0; i < 4; i++) {
                int n = 16 * m + 4 * kg + i;
                int gn = n0 + n;
                if (gn < NN) {
                    float lin = gacc[m][t][i] + b;
                    float gt = 1.f / (1.f + expf(-lin));
                    float pv = unpack_bf(o_pk[n * FSTR + fcol]);
                    float ov = pv + pacc[m][t][i];
                    out[(size_t)gn * OD + dual_off + fcol] = gt * ov + (1.f - gt) * pv;
                }
            }
    }
}

extern "C" void kernel_launch(void* const* d_in, const int* in_sizes, int n_in,
                              void* d_out, int out_size, void* d_ws, size_t ws_size,
                              hipStream_t stream) {
    const float* ent_emb = (const float*)d_in[0];
    const float* rel_emb = (const float*)d_in[1];
    const int* e_src     = (const int*)d_in[2];
    const int* e_dst     = (const int*)d_in[3];
    const int* e_rel     = (const int*)d_in[4];
    const float* attn_e  = (const float*)d_in[5];
    const float* gate_e  = (const float*)d_in[6];
    const float* proxy_e = (const float*)d_in[7];
    const float* bias_e  = (const float*)d_in[8];
    const float* attn_r  = (const float*)d_in[9];
    const float* gate_r  = (const float*)d_in[10];
    const float* proxy_r = (const float*)d_in[11];
    const float* bias_r  = (const float*)d_in[12];
    float* out = (float*)d_out;
    (void)d_ws; (void)ws_size; (void)in_sizes; (void)n_in; (void)out_size;

    k_zero<<<(NN + 255) / 256, 256, 0, stream>>>();
    k_prep_rel<<<NR / 4, 256, 0, stream>>>(rel_emb, attn_e, attn_r);
    k_prep_ent<<<(NN * FF / 8 + 255) / 256, 256, 0, stream>>>(ent_emb);
    k_prep_proxy<<<32, 256, 0, stream>>>(proxy_e, proxy_r);
    k_prep_wt<<<(2 * FDIM * FDIM + 255) / 256, 256, 0, stream>>>(gate_e, gate_r);
    k_count<<<(NE + 255) / 256, 256, 0, stream>>>(e_dst);
    k_scan1<<<NBLK, 1024, 0, stream>>>();
    k_scan2<<<1, 64, 0, stream>>>();
    k_scan3<<<NBLK, 1024, 0, stream>>>();
    k_fill<<<(NE + 255) / 256, 256, 0, stream>>>(e_src, e_dst, e_rel);
    k_init<<<NN / 4, 256, 0, stream>>>(rel_emb, out);
    k_layer<<<NN / 4, 256, 0, stream>>>(out, 0);
    k_layer<<<NN / 4, 256, 0, stream>>>(out, 1);
    k_pg<<<dim3((NN + NPB - 1) / NPB, 2), 256, 0, stream>>>(out, bias_e, bias_r);
}